// Round 1
// baseline (1098.573 us; speedup 1.0000x reference)
//
#include <hip/hip_runtime.h>
#include <cstdint>

#define Bz 8
#define Nn 1024
#define Cc 768
#define Hh 12
#define Dd 64
#define C3 2304
#define BN 8192

constexpr float SCALE = 0.125f;   // 64^-0.5
constexpr float EPS = 1e-5f;

// ---------------- GEMM NT with bias: Out[m,n] = sum_k A[m,k]*W[n,k] + bias[n] ----------------
// A: [M, K] row stride lda; W: [Nout, K] row-major; Out: [M, Nout] row stride ldo.
// TM=TN=128, TK=32, 256 threads, 8x8 per thread.
template<int TM, int TN, int TK>
__global__ __launch_bounds__(256) void gemm_nt_bias(
    const float* __restrict__ A, int lda,
    const float* __restrict__ W,
    const float* __restrict__ bias,
    float* __restrict__ Out, int ldo,
    int K)
{
    __shared__ float as[TK][TM + 4];   // [k][m] (transposed for float4 fragment reads)
    __shared__ float bs[TK][TN + 4];
    const int tid = threadIdx.x;
    const int tx = tid & 15, ty = tid >> 4;
    const int m0 = blockIdx.y * TM;
    const int n0 = blockIdx.x * TN;
    float acc[8][8] = {};
    for (int k0 = 0; k0 < K; k0 += TK) {
#pragma unroll
        for (int l = 0; l < (TM * TK) / (256 * 4); ++l) {
            int idx = tid + l * 256;       // 0..1023
            int m = idx >> 3;              // TK/4 = 8 float4 per row
            int kq = idx & 7;
            float4 f = *(const float4*)&A[(size_t)(m0 + m) * lda + k0 + kq * 4];
            as[kq * 4 + 0][m] = f.x; as[kq * 4 + 1][m] = f.y;
            as[kq * 4 + 2][m] = f.z; as[kq * 4 + 3][m] = f.w;
            float4 g = *(const float4*)&W[(size_t)(n0 + m) * K + k0 + kq * 4];
            bs[kq * 4 + 0][m] = g.x; bs[kq * 4 + 1][m] = g.y;
            bs[kq * 4 + 2][m] = g.z; bs[kq * 4 + 3][m] = g.w;
        }
        __syncthreads();
#pragma unroll
        for (int kk = 0; kk < TK; ++kk) {
            float a[8], b[8];
            *(float4*)&a[0] = *(const float4*)&as[kk][ty * 8];
            *(float4*)&a[4] = *(const float4*)&as[kk][ty * 8 + 4];
            *(float4*)&b[0] = *(const float4*)&bs[kk][tx * 8];
            *(float4*)&b[4] = *(const float4*)&bs[kk][tx * 8 + 4];
#pragma unroll
            for (int i = 0; i < 8; ++i)
#pragma unroll
                for (int j = 0; j < 8; ++j)
                    acc[i][j] += a[i] * b[j];
        }
        __syncthreads();
    }
#pragma unroll
    for (int i = 0; i < 8; ++i) {
        int m = m0 + ty * 8 + i;
#pragma unroll
        for (int j4 = 0; j4 < 8; j4 += 4) {
            int n = n0 + tx * 8 + j4;
            float4 r;
            r.x = acc[i][j4 + 0] + bias[n + 0];
            r.y = acc[i][j4 + 1] + bias[n + 1];
            r.z = acc[i][j4 + 2] + bias[n + 2];
            r.w = acc[i][j4 + 3] + bias[n + 3];
            *(float4*)&Out[(size_t)m * ldo + n] = r;
        }
    }
}

// ---------------- LayerNorm of q and k rows (D=64, one wave per row) ----------------
__global__ __launch_bounds__(256) void qk_layernorm(
    float* __restrict__ qkv,
    const float* __restrict__ qg, const float* __restrict__ qb,
    const float* __restrict__ kg, const float* __restrict__ kb)
{
    const int lane = threadIdx.x & 63;
    const int wv = threadIdx.x >> 6;
    const int row = blockIdx.x * 4 + wv;       // [0, BN*H*2)
    const int bn = row / 24;                   // H*2 = 24
    const int rem = row - bn * 24;
    const int h = rem >> 1;
    const int t = rem & 1;                     // 0 = q, 1 = k
    const size_t addr = (size_t)bn * C3 + (size_t)t * Cc + h * 64 + lane;
    float v = qkv[addr];
    float s = v;
#pragma unroll
    for (int off = 1; off < 64; off <<= 1) s += __shfl_xor(s, off);
    const float mu = s * (1.0f / 64.0f);
    const float d = v - mu;
    float s2 = d * d;
#pragma unroll
    for (int off = 1; off < 64; off <<= 1) s2 += __shfl_xor(s2, off);
    const float inv = rsqrtf(s2 * (1.0f / 64.0f) + EPS);
    const float g = t ? kg[lane] : qg[lane];
    const float bb = t ? kb[lane] : qb[lane];
    float r = d * inv * g + bb;
    if (!t) r *= SCALE;
    qkv[addr] = r;
}

// ---------------- Flash attention (fp32). One block per (b, h, q-tile of 64). ----------------
// Reads q/k/v from qkv buffer [B,N,3C]; writes attention output OVER the q region
// (same rows/cols it consumed, so no cross-block hazard).
__global__ __launch_bounds__(256) void flash_attn(float* __restrict__ qkv)
{
    __shared__ float qs[64][68];   // [d][qrow]
    __shared__ float kp[64][68];   // K transposed [d][krow] during S; reused as P [qrow][k] for PV
    __shared__ float vs[64][68];   // [krow][d]
    const int tid = threadIdx.x;
    const int tx = tid & 15, ty = tid >> 4;
    const int bid = blockIdx.x;
    const int qt = bid & 15;
    const int bh = bid >> 4;
    const int h = bh % Hh;
    const int b = bh / Hh;
    float* base = qkv + (size_t)b * Nn * C3;

    // stage Q tile transposed: qs[d][r]
#pragma unroll
    for (int l = 0; l < 4; ++l) {
        int idx = tid + l * 256;
        int r = idx >> 4, dq = idx & 15;
        float4 f = *(const float4*)(base + (size_t)(qt * 64 + r) * C3 + h * 64 + dq * 4);
        qs[dq * 4 + 0][r] = f.x; qs[dq * 4 + 1][r] = f.y;
        qs[dq * 4 + 2][r] = f.z; qs[dq * 4 + 3][r] = f.w;
    }

    float o[4][4] = {};
    float mrun[4], lrun[4];
#pragma unroll
    for (int i = 0; i < 4; ++i) { mrun[i] = -1e30f; lrun[i] = 0.f; }

    for (int kt = 0; kt < 16; ++kt) {
        __syncthreads();   // previous iteration's readers of kp/vs are done (also orders qs stores at kt=0)
        // stage K transposed + V natural
#pragma unroll
        for (int l = 0; l < 4; ++l) {
            int idx = tid + l * 256;
            int r = idx >> 4, dq = idx & 15;
            float4 f = *(const float4*)(base + (size_t)(kt * 64 + r) * C3 + Cc + h * 64 + dq * 4);
            kp[dq * 4 + 0][r] = f.x; kp[dq * 4 + 1][r] = f.y;
            kp[dq * 4 + 2][r] = f.z; kp[dq * 4 + 3][r] = f.w;
            float4 g = *(const float4*)(base + (size_t)(kt * 64 + r) * C3 + 2 * Cc + h * 64 + dq * 4);
            *(float4*)&vs[r][dq * 4] = g;
        }
        __syncthreads();
        // S = Q K^T; s[i][j] at (row ty*4+i, col tx*4+j)
        float s[4][4] = {};
#pragma unroll
        for (int dd = 0; dd < 64; ++dd) {
            float a[4], c[4];
            *(float4*)a = *(const float4*)&qs[dd][ty * 4];
            *(float4*)c = *(const float4*)&kp[dd][tx * 4];
#pragma unroll
            for (int i = 0; i < 4; ++i)
#pragma unroll
                for (int j = 0; j < 4; ++j) s[i][j] += a[i] * c[j];
        }
        // online softmax (row stats across the 16-lane tx group)
#pragma unroll
        for (int i = 0; i < 4; ++i) {
            float rm = fmaxf(fmaxf(s[i][0], s[i][1]), fmaxf(s[i][2], s[i][3]));
#pragma unroll
            for (int off = 1; off < 16; off <<= 1) rm = fmaxf(rm, __shfl_xor(rm, off));
            float mnew = fmaxf(mrun[i], rm);
            float resc = __expf(mrun[i] - mnew);
            mrun[i] = mnew;
            float rs = 0.f;
#pragma unroll
            for (int j = 0; j < 4; ++j) { s[i][j] = __expf(s[i][j] - mnew); rs += s[i][j]; }
#pragma unroll
            for (int off = 1; off < 16; off <<= 1) rs += __shfl_xor(rs, off);
            lrun[i] = lrun[i] * resc + rs;
#pragma unroll
            for (int j = 0; j < 4; ++j) o[i][j] *= resc;
        }
        __syncthreads();   // all S-phase reads of kp complete before P overwrites it
#pragma unroll
        for (int i = 0; i < 4; ++i)
            *(float4*)&kp[ty * 4 + i][tx * 4] = *(float4*)&s[i][0];
        __syncthreads();
        // O += P V ; o[i][j] at (row ty*4+i, dcol tx*4+j)
#pragma unroll
        for (int kk = 0; kk < 64; ++kk) {
            float pv[4], vv[4];
#pragma unroll
            for (int i = 0; i < 4; ++i) pv[i] = kp[ty * 4 + i][kk];
            *(float4*)vv = *(const float4*)&vs[kk][tx * 4];
#pragma unroll
            for (int i = 0; i < 4; ++i)
#pragma unroll
                for (int j = 0; j < 4; ++j) o[i][j] += pv[i] * vv[j];
        }
    }
    // epilogue: write over the q region (att layout [B,N,C] at col h*64+dc, row stride C3)
#pragma unroll
    for (int i = 0; i < 4; ++i) {
        float invl = 1.0f / lrun[i];
        float4 r;
        r.x = o[i][0] * invl; r.y = o[i][1] * invl;
        r.z = o[i][2] * invl; r.w = o[i][3] * invl;
        *(float4*)(base + (size_t)(qt * 64 + ty * 4 + i) * C3 + h * 64 + tx * 4) = r;
    }
}

extern "C" void kernel_launch(void* const* d_in, const int* in_sizes, int n_in,
                              void* d_out, int out_size, void* d_ws, size_t ws_size,
                              hipStream_t stream)
{
    const float* x      = (const float*)d_in[0];
    const float* qkv_w  = (const float*)d_in[1];
    const float* qkv_b  = (const float*)d_in[2];
    const float* qn_g   = (const float*)d_in[3];
    const float* qn_b   = (const float*)d_in[4];
    const float* kn_g   = (const float*)d_in[5];
    const float* kn_b   = (const float*)d_in[6];
    const float* proj_w = (const float*)d_in[7];
    const float* proj_b = (const float*)d_in[8];
    float* qkv = (float*)d_ws;            // [BN, 3C] fp32 = 75.5 MB
    float* out = (float*)d_out;

    // 1) QKV projection + bias
    gemm_nt_bias<128, 128, 32><<<dim3(C3 / 128, BN / 128), 256, 0, stream>>>(
        x, Cc, qkv_w, qkv_b, qkv, C3, Cc);
    // 2) LayerNorm(q)*SCALE, LayerNorm(k) in place
    qk_layernorm<<<(BN * Hh * 2) / 4, 256, 0, stream>>>(qkv, qn_g, qn_b, kn_g, kn_b);
    // 3) flash attention; output overwrites the q region of qkv (row stride C3)
    flash_attn<<<Bz * Hh * 16, 256, 0, stream>>>(qkv);
    // 4) output projection + bias
    gemm_nt_bias<128, 128, 32><<<dim3(Cc / 128, BN / 128), 256, 0, stream>>>(
        qkv, C3, proj_w, proj_b, out, Cc, Cc);
}

// Round 2
// 670.351 us; speedup vs baseline: 1.6388x; 1.6388x over previous
//
#include <hip/hip_runtime.h>
#include <cstdint>

#define Bz 8
#define Nn 1024
#define Cc 768
#define Hh 12
#define Dd 64
#define C3 2304
#define BN 8192

constexpr float SCALE = 0.125f;   // 64^-0.5
constexpr float EPS = 1e-5f;

typedef __attribute__((ext_vector_type(8))) short bf16x8;
typedef __attribute__((ext_vector_type(4))) float f32x4;

__device__ __forceinline__ short f2b(float f) {
    union { float f; unsigned u; } x; x.f = f;
    unsigned r = x.u + 0x7FFFu + ((x.u >> 16) & 1u);   // RNE to bf16
    return (short)(r >> 16);
}

__device__ __forceinline__ f32x4 MFMA(bf16x8 a, bf16x8 b, f32x4 c) {
    return __builtin_amdgcn_mfma_f32_16x16x32_bf16(a, b, c, 0, 0, 0);
}

// ---------------- GEMM NT with bias: Out[m,n] = sum_k A[m,k]*W[n,k] + bias[n] ----------------
template<int TM, int TN, int TK>
__global__ __launch_bounds__(256) void gemm_nt_bias(
    const float* __restrict__ A, int lda,
    const float* __restrict__ W,
    const float* __restrict__ bias,
    float* __restrict__ Out, int ldo,
    int K)
{
    __shared__ float as[TK][TM + 4];
    __shared__ float bs[TK][TN + 4];
    const int tid = threadIdx.x;
    const int tx = tid & 15, ty = tid >> 4;
    const int m0 = blockIdx.y * TM;
    const int n0 = blockIdx.x * TN;
    float acc[8][8] = {};
    for (int k0 = 0; k0 < K; k0 += TK) {
#pragma unroll
        for (int l = 0; l < (TM * TK) / (256 * 4); ++l) {
            int idx = tid + l * 256;
            int m = idx >> 3;
            int kq = idx & 7;
            float4 f = *(const float4*)&A[(size_t)(m0 + m) * lda + k0 + kq * 4];
            as[kq * 4 + 0][m] = f.x; as[kq * 4 + 1][m] = f.y;
            as[kq * 4 + 2][m] = f.z; as[kq * 4 + 3][m] = f.w;
            float4 g = *(const float4*)&W[(size_t)(n0 + m) * K + k0 + kq * 4];
            bs[kq * 4 + 0][m] = g.x; bs[kq * 4 + 1][m] = g.y;
            bs[kq * 4 + 2][m] = g.z; bs[kq * 4 + 3][m] = g.w;
        }
        __syncthreads();
#pragma unroll
        for (int kk = 0; kk < TK; ++kk) {
            float a[8], b[8];
            *(float4*)&a[0] = *(const float4*)&as[kk][ty * 8];
            *(float4*)&a[4] = *(const float4*)&as[kk][ty * 8 + 4];
            *(float4*)&b[0] = *(const float4*)&bs[kk][tx * 8];
            *(float4*)&b[4] = *(const float4*)&bs[kk][tx * 8 + 4];
#pragma unroll
            for (int i = 0; i < 8; ++i)
#pragma unroll
                for (int j = 0; j < 8; ++j)
                    acc[i][j] += a[i] * b[j];
        }
        __syncthreads();
    }
#pragma unroll
    for (int i = 0; i < 8; ++i) {
        int m = m0 + ty * 8 + i;
#pragma unroll
        for (int j4 = 0; j4 < 8; j4 += 4) {
            int n = n0 + tx * 8 + j4;
            float4 r;
            r.x = acc[i][j4 + 0] + bias[n + 0];
            r.y = acc[i][j4 + 1] + bias[n + 1];
            r.z = acc[i][j4 + 2] + bias[n + 2];
            r.w = acc[i][j4 + 3] + bias[n + 3];
            *(float4*)&Out[(size_t)m * ldo + n] = r;
        }
    }
}

// ---------------- LayerNorm of q and k rows (D=64, one wave per row) ----------------
__global__ __launch_bounds__(256) void qk_layernorm(
    float* __restrict__ qkv,
    const float* __restrict__ qg, const float* __restrict__ qb,
    const float* __restrict__ kg, const float* __restrict__ kb)
{
    const int lane = threadIdx.x & 63;
    const int wv = threadIdx.x >> 6;
    const int row = blockIdx.x * 4 + wv;
    const int bn = row / 24;
    const int rem = row - bn * 24;
    const int h = rem >> 1;
    const int t = rem & 1;
    const size_t addr = (size_t)bn * C3 + (size_t)t * Cc + h * 64 + lane;
    float v = qkv[addr];
    float s = v;
#pragma unroll
    for (int off = 1; off < 64; off <<= 1) s += __shfl_xor(s, off);
    const float mu = s * (1.0f / 64.0f);
    const float d = v - mu;
    float s2 = d * d;
#pragma unroll
    for (int off = 1; off < 64; off <<= 1) s2 += __shfl_xor(s2, off);
    const float inv = rsqrtf(s2 * (1.0f / 64.0f) + EPS);
    const float g = t ? kg[lane] : qg[lane];
    const float bb = t ? kb[lane] : qb[lane];
    float r = d * inv * g + bb;
    if (!t) r *= SCALE;
    qkv[addr] = r;
}

// ---------------- Flash attention, bf16 MFMA. One block = (b, h, 128 q-rows). ----------------
// 4 waves x 32 q-rows. K/V staged per 64-k-tile as swizzled bf16 LDS (V transposed).
// Q staged once -> register fragments; Q LDS reused as per-wave P buffer.
// Output written fp32 over the q region of qkv.
__global__ __launch_bounds__(256) void flash_attn_mfma(float* __restrict__ qkv)
{
    __shared__ short qp[128 * 64];   // Q tile, then per-wave P (rows w*32..w*32+31)
    __shared__ short kls[64 * 64];   // K tile [k][d]
    __shared__ short vtl[64 * 64];   // V tile transposed [d][k]
    const int tid = threadIdx.x;
    const int lane = tid & 63;
    const int w = tid >> 6;
    const int l15 = lane & 15;
    const int l4 = lane >> 4;
    const int bid = blockIdx.x;
    const int qt = bid & 7;
    const int bh = bid >> 3;
    const int h = bh % Hh;
    const int b = bh / Hh;
    float* base = qkv + (size_t)b * Nn * C3;
    const int q0 = qt * 128;

    // ---- stage Q (128x64) as swizzled bf16
    {
        int r = tid >> 1, dh = (tid & 1) * 32;
        const float* src = base + (size_t)(q0 + r) * C3 + h * 64 + dh;
        float fv[32];
#pragma unroll
        for (int j = 0; j < 8; ++j) *(float4*)&fv[j * 4] = *(const float4*)(src + j * 4);
#pragma unroll
        for (int j = 0; j < 4; ++j) {
            bf16x8 t;
#pragma unroll
            for (int i = 0; i < 8; ++i) t[i] = f2b(fv[j * 8 + i]);
            *(bf16x8*)&qp[r * 64 + ((dh + j * 8) ^ ((r & 7) << 3))] = t;
        }
    }
    __syncthreads();
    // Q fragments -> registers
    bf16x8 qf[2][2];
#pragma unroll
    for (int mt = 0; mt < 2; ++mt)
#pragma unroll
        for (int ks = 0; ks < 2; ++ks) {
            int r = w * 32 + mt * 16 + l15;
            qf[mt][ks] = *(bf16x8*)&qp[r * 64 + ((ks * 32 + l4 * 8) ^ ((r & 7) << 3))];
        }

    f32x4 o[2][4];
    float mrun[2][4], lrun[2][4];
#pragma unroll
    for (int mt = 0; mt < 2; ++mt)
#pragma unroll
        for (int nt = 0; nt < 4; ++nt) { o[mt][nt][0] = 0.f; o[mt][nt][1] = 0.f; o[mt][nt][2] = 0.f; o[mt][nt][3] = 0.f; }
#pragma unroll
    for (int mt = 0; mt < 2; ++mt)
#pragma unroll
        for (int r = 0; r < 4; ++r) { mrun[mt][r] = -1e30f; lrun[mt][r] = 0.f; }

    for (int kt = 0; kt < 16; ++kt) {
        __syncthreads();   // prior K/V readers done
        // stage K tile (bf16, swizzled)
        {
            int r = tid >> 2, d0 = (tid & 3) * 16;
            const float* src = base + (size_t)(kt * 64 + r) * C3 + Cc + h * 64 + d0;
            float fv[16];
#pragma unroll
            for (int j = 0; j < 4; ++j) *(float4*)&fv[j * 4] = *(const float4*)(src + j * 4);
#pragma unroll
            for (int q = 0; q < 2; ++q) {
                bf16x8 t;
#pragma unroll
                for (int i = 0; i < 8; ++i) t[i] = f2b(fv[q * 8 + i]);
                *(bf16x8*)&kls[r * 64 + ((d0 + q * 8) ^ ((r & 7) << 3))] = t;
            }
        }
        // stage V tile transposed (bf16, swizzled): Vt[d][k]
        {
            int n0 = (tid & 31) * 2, d0 = (tid >> 5) * 8;
            const float* s0 = base + (size_t)(kt * 64 + n0) * C3 + 2 * Cc + h * 64 + d0;
            const float* s1 = s0 + C3;
            float a0[8], a1[8];
            *(float4*)&a0[0] = *(const float4*)s0; *(float4*)&a0[4] = *(const float4*)(s0 + 4);
            *(float4*)&a1[0] = *(const float4*)s1; *(float4*)&a1[4] = *(const float4*)(s1 + 4);
#pragma unroll
            for (int j = 0; j < 8; ++j) {
                int d = d0 + j;
                unsigned pk = (unsigned short)f2b(a0[j]) | ((unsigned)(unsigned short)f2b(a1[j]) << 16);
                *(unsigned*)&vtl[d * 64 + (n0 ^ ((d & 7) << 3))] = pk;
            }
        }
        __syncthreads();
        // S = Q K^T (per wave: 32 q-rows x 64 k-cols)
        f32x4 s[2][4];
#pragma unroll
        for (int nt = 0; nt < 4; ++nt) {
            int r = nt * 16 + l15;
            bf16x8 kf0 = *(bf16x8*)&kls[r * 64 + ((l4 * 8) ^ ((r & 7) << 3))];
            bf16x8 kf1 = *(bf16x8*)&kls[r * 64 + ((32 + l4 * 8) ^ ((r & 7) << 3))];
#pragma unroll
            for (int mt = 0; mt < 2; ++mt) {
                f32x4 acc; acc[0] = 0.f; acc[1] = 0.f; acc[2] = 0.f; acc[3] = 0.f;
                acc = MFMA(qf[mt][0], kf0, acc);
                acc = MFMA(qf[mt][1], kf1, acc);
                s[mt][nt] = acc;
            }
        }
        // online softmax (rows across 16-lane col groups)
#pragma unroll
        for (int mt = 0; mt < 2; ++mt) {
#pragma unroll
            for (int r = 0; r < 4; ++r) {
                float rowm = fmaxf(fmaxf(s[mt][0][r], s[mt][1][r]), fmaxf(s[mt][2][r], s[mt][3][r]));
#pragma unroll
                for (int off = 1; off < 16; off <<= 1) rowm = fmaxf(rowm, __shfl_xor(rowm, off));
                float mnew = fmaxf(mrun[mt][r], rowm);
                float resc = __expf(mrun[mt][r] - mnew);
                mrun[mt][r] = mnew;
                float ps = 0.f;
#pragma unroll
                for (int nt = 0; nt < 4; ++nt) {
                    float p = __expf(s[mt][nt][r] - mnew);
                    s[mt][nt][r] = p;
                    ps += p;
                }
#pragma unroll
                for (int off = 1; off < 16; off <<= 1) ps += __shfl_xor(ps, off);
                lrun[mt][r] = lrun[mt][r] * resc + ps;
#pragma unroll
                for (int nt = 0; nt < 4; ++nt) o[mt][nt][r] *= resc;
            }
        }
        // write P (bf16) into wave-private rows of qp
#pragma unroll
        for (int mt = 0; mt < 2; ++mt)
#pragma unroll
            for (int r = 0; r < 4; ++r) {
                int row = w * 32 + mt * 16 + l4 * 4 + r;
#pragma unroll
                for (int nt = 0; nt < 4; ++nt)
                    qp[row * 64 + ((nt * 16 + l15) ^ ((row & 7) << 3))] = f2b(s[mt][nt][r]);
            }
        // O += P V
#pragma unroll
        for (int ks = 0; ks < 2; ++ks) {
            bf16x8 pf[2];
#pragma unroll
            for (int mt = 0; mt < 2; ++mt) {
                int row = w * 32 + mt * 16 + l15;
                pf[mt] = *(bf16x8*)&qp[row * 64 + ((ks * 32 + l4 * 8) ^ ((row & 7) << 3))];
            }
#pragma unroll
            for (int nt = 0; nt < 4; ++nt) {
                int d = nt * 16 + l15;
                bf16x8 vf = *(bf16x8*)&vtl[d * 64 + ((ks * 32 + l4 * 8) ^ ((d & 7) << 3))];
#pragma unroll
                for (int mt = 0; mt < 2; ++mt)
                    o[mt][nt] = MFMA(pf[mt], vf, o[mt][nt]);
            }
        }
    }
    // epilogue: O /= l, write fp32 over q region
#pragma unroll
    for (int mt = 0; mt < 2; ++mt)
#pragma unroll
        for (int r = 0; r < 4; ++r) {
            float inv = 1.0f / lrun[mt][r];
            int row = q0 + w * 32 + mt * 16 + l4 * 4 + r;
            float* dst = base + (size_t)row * C3 + h * 64 + l15;
#pragma unroll
            for (int nt = 0; nt < 4; ++nt)
                dst[nt * 16] = o[mt][nt][r] * inv;
        }
}

extern "C" void kernel_launch(void* const* d_in, const int* in_sizes, int n_in,
                              void* d_out, int out_size, void* d_ws, size_t ws_size,
                              hipStream_t stream)
{
    const float* x      = (const float*)d_in[0];
    const float* qkv_w  = (const float*)d_in[1];
    const float* qkv_b  = (const float*)d_in[2];
    const float* qn_g   = (const float*)d_in[3];
    const float* qn_b   = (const float*)d_in[4];
    const float* kn_g   = (const float*)d_in[5];
    const float* kn_b   = (const float*)d_in[6];
    const float* proj_w = (const float*)d_in[7];
    const float* proj_b = (const float*)d_in[8];
    float* qkv = (float*)d_ws;            // [BN, 3C] fp32 = 75.5 MB
    float* out = (float*)d_out;

    // 1) QKV projection + bias
    gemm_nt_bias<128, 128, 32><<<dim3(C3 / 128, BN / 128), 256, 0, stream>>>(
        x, Cc, qkv_w, qkv_b, qkv, C3, Cc);
    // 2) LayerNorm(q)*SCALE, LayerNorm(k) in place
    qk_layernorm<<<(BN * Hh * 2) / 4, 256, 0, stream>>>(qkv, qn_g, qn_b, kn_g, kn_b);
    // 3) flash attention (bf16 MFMA); output overwrites q region of qkv
    flash_attn_mfma<<<Bz * Hh * 8, 256, 0, stream>>>(qkv);
    // 4) output projection + bias
    gemm_nt_bias<128, 128, 32><<<dim3(Cc / 128, BN / 128), 256, 0, stream>>>(
        qkv, C3, proj_w, proj_b, out, Cc, Cc);
}

// Round 3
// 184.022 us; speedup vs baseline: 5.9698x; 3.6428x over previous
//
#include <hip/hip_runtime.h>
#include <cstdint>

#define Bz 8
#define Nn 1024
#define Cc 768
#define Hh 12
#define Dd 64
#define C3 2304
#define BN 8192

constexpr float SCALE = 0.125f;   // 64^-0.5
constexpr float EPS = 1e-5f;

typedef __attribute__((ext_vector_type(8))) short bf16x8;
typedef _Float16 f16x8 __attribute__((ext_vector_type(8)));
typedef __attribute__((ext_vector_type(4))) float f32x4;

__device__ __forceinline__ short f2b(float f) {
    union { float f; unsigned u; } x; x.f = f;
    unsigned r = x.u + 0x7FFFu + ((x.u >> 16) & 1u);   // RNE to bf16
    return (short)(r >> 16);
}

__device__ __forceinline__ f32x4 MFMAB(bf16x8 a, bf16x8 b, f32x4 c) {
    return __builtin_amdgcn_mfma_f32_16x16x32_bf16(a, b, c, 0, 0, 0);
}
__device__ __forceinline__ f32x4 MFMAH(f16x8 a, f16x8 b, f32x4 c) {
    return __builtin_amdgcn_mfma_f32_16x16x32_f16(a, b, c, 0, 0, 0);
}
// async global->LDS, 16B per lane; lds dst is wave-uniform base (+lane*16 by HW)
__device__ __forceinline__ void gld16(const void* g, void* l) {
    __builtin_amdgcn_global_load_lds((const __attribute__((address_space(1))) unsigned int*)g,
                                     (__attribute__((address_space(3))) unsigned int*)(l),
                                     16, 0, 0);
}

// ---------------- fp32 -> fp16 convert (8 elems/thread) ----------------
__global__ __launch_bounds__(256) void f32_to_f16_k(const float* __restrict__ s,
                                                    _Float16* __restrict__ d, int n8)
{
    int i = blockIdx.x * 256 + threadIdx.x;
    if (i >= n8) return;
    float4 a = *(const float4*)(s + (size_t)i * 8);
    float4 b = *(const float4*)(s + (size_t)i * 8 + 4);
    f16x8 o;
    o[0] = (_Float16)a.x; o[1] = (_Float16)a.y; o[2] = (_Float16)a.z; o[3] = (_Float16)a.w;
    o[4] = (_Float16)b.x; o[5] = (_Float16)b.y; o[6] = (_Float16)b.z; o[7] = (_Float16)b.w;
    *(f16x8*)(d + (size_t)i * 8) = o;
}

// ---------------- fp16 MFMA GEMM NT: Out[m,n] = sum_k A[m,k]*W[n,k] + bias[n] ----------------
// A:[M][768] fp16, W:[Ntot][768] fp16. 128x128 tile, BK=64, 4 waves (2x2), 64x64/wave.
// EPI=0: fp32 out [M][768] + bias (proj). EPI=1: bias + LN(q)*SCALE / LN(k) fused,
//        write bf16 planes qp/kp/vp [M][12][64].
template<int EPI>
__global__ __launch_bounds__(256) void gemm_f16(
    const _Float16* __restrict__ A,
    const _Float16* __restrict__ W,
    const float* __restrict__ bias,
    float* __restrict__ Out,
    short* __restrict__ qp, short* __restrict__ kp, short* __restrict__ vp,
    const float* __restrict__ qg, const float* __restrict__ qb,
    const float* __restrict__ kg, const float* __restrict__ kb)
{
    __shared__ _Float16 As[128 * 64];   // [row][64k], 128B rows, slot-swizzled
    __shared__ _Float16 Bs[128 * 64];
    const int tid = threadIdx.x;
    const int lane = tid & 63;
    const int w = tid >> 6;
    const int wr = w >> 1, wc = w & 1;
    const int l15 = lane & 15, l4 = lane >> 4;
    const int m0 = blockIdx.y * 128;
    const int n0 = blockIdx.x * 128;
    const int lr = lane >> 3;        // row within an 8-row issue
    const int lslot = lane & 7;      // 16B slot within 128B row

    f32x4 acc[4][4];
#pragma unroll
    for (int mi = 0; mi < 4; ++mi)
#pragma unroll
        for (int ni = 0; ni < 4; ++ni) { acc[mi][ni][0]=0.f; acc[mi][ni][1]=0.f; acc[mi][ni][2]=0.f; acc[mi][ni][3]=0.f; }

    for (int kt = 0; kt < 12; ++kt) {
        const int k0 = kt * 64;
        // stage: 32 x 1KB issues (16 A + 16 B), 8 per wave; source pre-swizzled
#pragma unroll
        for (int j = 0; j < 8; ++j) {
            int i = w * 8 + j;
            int isA = (i < 16);
            int ib = isA ? i : i - 16;
            int row = ib * 8 + lr;                 // tile-local 0..127
            int gslot = lslot ^ (row & 7);
            const _Float16* src = (isA ? A + (size_t)(m0 + row) * 768
                                       : W + (size_t)(n0 + row) * 768) + k0 + gslot * 8;
            _Float16* dst = (isA ? As : Bs) + ib * 512;   // wave-uniform
            gld16(src, dst);
        }
        __syncthreads();
#pragma unroll
        for (int ks = 0; ks < 2; ++ks) {
            f16x8 af[4], bfr[4];
#pragma unroll
            for (int mi = 0; mi < 4; ++mi) {
                int row = wr * 64 + mi * 16 + l15;
                int slot = (ks * 4 + l4) ^ (row & 7);
                af[mi] = *(const f16x8*)&As[row * 64 + slot * 8];
            }
#pragma unroll
            for (int ni = 0; ni < 4; ++ni) {
                int row = wc * 64 + ni * 16 + l15;
                int slot = (ks * 4 + l4) ^ (row & 7);
                bfr[ni] = *(const f16x8*)&Bs[row * 64 + slot * 8];
            }
#pragma unroll
            for (int mi = 0; mi < 4; ++mi)
#pragma unroll
                for (int ni = 0; ni < 4; ++ni)
                    acc[mi][ni] = MFMAH(af[mi], bfr[ni], acc[mi][ni]);
        }
        __syncthreads();
    }

    if (EPI == 0) {
#pragma unroll
        for (int mi = 0; mi < 4; ++mi)
#pragma unroll
            for (int r = 0; r < 4; ++r) {
                int row = m0 + wr * 64 + mi * 16 + l4 * 4 + r;
#pragma unroll
                for (int ni = 0; ni < 4; ++ni) {
                    int col = n0 + wc * 64 + ni * 16 + l15;
                    Out[(size_t)row * Cc + col] = acc[mi][ni][r] + bias[col];
                }
            }
    } else {
        // wave's 64-col block = exactly one head of q, k, or v
        const int ncol0 = n0 + wc * 64;
        const int type = ncol0 / Cc;           // 0=q 1=k 2=v  (wave-uniform)
        const int h = (ncol0 % Cc) >> 6;
        const float* gptr = (type == 0) ? qg : kg;
        const float* bptr = (type == 0) ? qb : kb;
        float biasv[4], gv[4], bv[4];
#pragma unroll
        for (int ni = 0; ni < 4; ++ni) {
            int d = ni * 16 + l15;
            biasv[ni] = bias[ncol0 + d];
            if (type < 2) { gv[ni] = gptr[d]; bv[ni] = bptr[d]; }
        }
        short* plane = (type == 0) ? qp : (type == 1) ? kp : vp;
#pragma unroll
        for (int mi = 0; mi < 4; ++mi)
#pragma unroll
            for (int r = 0; r < 4; ++r) {
                float v[4];
#pragma unroll
                for (int ni = 0; ni < 4; ++ni) v[ni] = acc[mi][ni][r] + biasv[ni];
                int row = m0 + wr * 64 + mi * 16 + l4 * 4 + r;
                size_t base = ((size_t)row * Hh + h) * 64;
                if (type < 2) {
                    float s = v[0] + v[1] + v[2] + v[3];
#pragma unroll
                    for (int off = 1; off < 16; off <<= 1) s += __shfl_xor(s, off);
                    float mu = s * (1.0f / 64.0f);
                    float s2 = 0.f;
#pragma unroll
                    for (int ni = 0; ni < 4; ++ni) { float dv = v[ni] - mu; s2 += dv * dv; }
#pragma unroll
                    for (int off = 1; off < 16; off <<= 1) s2 += __shfl_xor(s2, off);
                    float inv = rsqrtf(s2 * (1.0f / 64.0f) + EPS);
#pragma unroll
                    for (int ni = 0; ni < 4; ++ni) {
                        float rr = (v[ni] - mu) * inv * gv[ni] + bv[ni];
                        if (type == 0) rr *= SCALE;
                        plane[base + ni * 16 + l15] = f2b(rr);
                    }
                } else {
#pragma unroll
                    for (int ni = 0; ni < 4; ++ni)
                        plane[base + ni * 16 + l15] = f2b(v[ni]);
                }
            }
    }
}

// ---------------- Flash attention, bf16 MFMA, reads bf16 planes, writes fp16 att ----------------
__global__ __launch_bounds__(256) void flash_attn_mfma(
    const short* __restrict__ qp, const short* __restrict__ kp, const short* __restrict__ vp,
    _Float16* __restrict__ att)
{
    __shared__ short qpl[128 * 64];   // Q tile, then per-wave P rows
    __shared__ short kls[64 * 64];    // K tile [k][d] swizzled
    __shared__ short vtl[64 * 64];    // V^T tile [d][k] swizzled
    const int tid = threadIdx.x;
    const int lane = tid & 63;
    const int w = tid >> 6;
    const int l15 = lane & 15, l4 = lane >> 4;
    const int lr = lane >> 3, lslot = lane & 7;
    const int bid = blockIdx.x;
    const int qt = bid & 7;
    const int bh = bid >> 3;
    const int h = bh % Hh;
    const int b = bh / Hh;
    const int q0 = qt * 128;
    const size_t hbase = ((size_t)b * Nn * Hh + h) * 64;   // + seq*768

    // stage Q (128x64 bf16) via global_load_lds, source pre-swizzled
#pragma unroll
    for (int j = 0; j < 4; ++j) {
        int i = w * 4 + j;
        int row = i * 8 + lr;
        int gslot = lslot ^ (row & 7);
        gld16(qp + hbase + (size_t)(q0 + row) * 768 + gslot * 8, &qpl[i * 512]);
    }
    __syncthreads();
    bf16x8 qf[2][2];
#pragma unroll
    for (int mt = 0; mt < 2; ++mt)
#pragma unroll
        for (int ks = 0; ks < 2; ++ks) {
            int r = w * 32 + mt * 16 + l15;
            qf[mt][ks] = *(bf16x8*)&qpl[r * 64 + ((ks * 32 + l4 * 8) ^ ((r & 7) << 3))];
        }

    f32x4 o[2][4];
    float mrun[2][4], lrun[2][4];
#pragma unroll
    for (int mt = 0; mt < 2; ++mt)
#pragma unroll
        for (int nt = 0; nt < 4; ++nt) { o[mt][nt][0]=0.f; o[mt][nt][1]=0.f; o[mt][nt][2]=0.f; o[mt][nt][3]=0.f; }
#pragma unroll
    for (int mt = 0; mt < 2; ++mt)
#pragma unroll
        for (int r = 0; r < 4; ++r) { mrun[mt][r] = -1e30f; lrun[mt][r] = 0.f; }

    for (int kt = 0; kt < 16; ++kt) {
        __syncthreads();   // prior readers of kls/vtl done (and qf reads at kt=0)
        // stage K tile via gld (8 issues, 2/wave)
#pragma unroll
        for (int j = 0; j < 2; ++j) {
            int i = w * 2 + j;
            int row = i * 8 + lr;
            int gslot = lslot ^ (row & 7);
            gld16(kp + hbase + (size_t)(kt * 64 + row) * 768 + gslot * 8, &kls[i * 512]);
        }
        // stage V transposed (reg path)
        {
            int n0v = (tid & 31) * 2, d0 = (tid >> 5) * 8;
            const short* s0 = vp + hbase + (size_t)(kt * 64 + n0v) * 768 + d0;
            bf16x8 a0 = *(const bf16x8*)s0;
            bf16x8 a1 = *(const bf16x8*)(s0 + 768);
#pragma unroll
            for (int j = 0; j < 8; ++j) {
                int d = d0 + j;
                unsigned pk = (unsigned short)a0[j] | ((unsigned)(unsigned short)a1[j] << 16);
                *(unsigned*)&vtl[d * 64 + (n0v ^ ((d & 7) << 3))] = pk;
            }
        }
        __syncthreads();
        // S = Q K^T
        f32x4 s[2][4];
#pragma unroll
        for (int nt = 0; nt < 4; ++nt) {
            int r = nt * 16 + l15;
            bf16x8 kf0 = *(bf16x8*)&kls[r * 64 + ((l4 * 8) ^ ((r & 7) << 3))];
            bf16x8 kf1 = *(bf16x8*)&kls[r * 64 + ((32 + l4 * 8) ^ ((r & 7) << 3))];
#pragma unroll
            for (int mt = 0; mt < 2; ++mt) {
                f32x4 a; a[0]=0.f; a[1]=0.f; a[2]=0.f; a[3]=0.f;
                a = MFMAB(qf[mt][0], kf0, a);
                a = MFMAB(qf[mt][1], kf1, a);
                s[mt][nt] = a;
            }
        }
        // online softmax
#pragma unroll
        for (int mt = 0; mt < 2; ++mt) {
#pragma unroll
            for (int r = 0; r < 4; ++r) {
                float rowm = fmaxf(fmaxf(s[mt][0][r], s[mt][1][r]), fmaxf(s[mt][2][r], s[mt][3][r]));
#pragma unroll
                for (int off = 1; off < 16; off <<= 1) rowm = fmaxf(rowm, __shfl_xor(rowm, off));
                float mnew = fmaxf(mrun[mt][r], rowm);
                float resc = __expf(mrun[mt][r] - mnew);
                mrun[mt][r] = mnew;
                float ps = 0.f;
#pragma unroll
                for (int nt = 0; nt < 4; ++nt) {
                    float p = __expf(s[mt][nt][r] - mnew);
                    s[mt][nt][r] = p;
                    ps += p;
                }
#pragma unroll
                for (int off = 1; off < 16; off <<= 1) ps += __shfl_xor(ps, off);
                lrun[mt][r] = lrun[mt][r] * resc + ps;
#pragma unroll
                for (int nt = 0; nt < 4; ++nt) o[mt][nt][r] *= resc;
            }
        }
        // P -> wave-private rows of qpl (bf16)
#pragma unroll
        for (int mt = 0; mt < 2; ++mt)
#pragma unroll
            for (int r = 0; r < 4; ++r) {
                int row = w * 32 + mt * 16 + l4 * 4 + r;
#pragma unroll
                for (int nt = 0; nt < 4; ++nt)
                    qpl[row * 64 + ((nt * 16 + l15) ^ ((row & 7) << 3))] = f2b(s[mt][nt][r]);
            }
        // O += P V
#pragma unroll
        for (int ks = 0; ks < 2; ++ks) {
            bf16x8 pf[2];
#pragma unroll
            for (int mt = 0; mt < 2; ++mt) {
                int row = w * 32 + mt * 16 + l15;
                pf[mt] = *(bf16x8*)&qpl[row * 64 + ((ks * 32 + l4 * 8) ^ ((row & 7) << 3))];
            }
#pragma unroll
            for (int nt = 0; nt < 4; ++nt) {
                int d = nt * 16 + l15;
                bf16x8 vf = *(bf16x8*)&vtl[d * 64 + ((ks * 32 + l4 * 8) ^ ((d & 7) << 3))];
#pragma unroll
                for (int mt = 0; mt < 2; ++mt)
                    o[mt][nt] = MFMAB(pf[mt], vf, o[mt][nt]);
            }
        }
    }
    // epilogue: fp16 att[B*N][768]
#pragma unroll
    for (int mt = 0; mt < 2; ++mt)
#pragma unroll
        for (int r = 0; r < 4; ++r) {
            float inv = 1.0f / lrun[mt][r];
            int row = q0 + w * 32 + mt * 16 + l4 * 4 + r;
            _Float16* dst = att + (size_t)(b * Nn + row) * Cc + h * 64 + l15;
#pragma unroll
            for (int nt = 0; nt < 4; ++nt)
                dst[nt * 16] = (_Float16)(o[mt][nt][r] * inv);
        }
}

extern "C" void kernel_launch(void* const* d_in, const int* in_sizes, int n_in,
                              void* d_out, int out_size, void* d_ws, size_t ws_size,
                              hipStream_t stream)
{
    const float* x      = (const float*)d_in[0];
    const float* qkv_w  = (const float*)d_in[1];
    const float* qkv_b  = (const float*)d_in[2];
    const float* qn_g   = (const float*)d_in[3];
    const float* qn_b   = (const float*)d_in[4];
    const float* kn_g   = (const float*)d_in[5];
    const float* kn_b   = (const float*)d_in[6];
    const float* proj_w = (const float*)d_in[7];
    const float* proj_b = (const float*)d_in[8];
    float* out = (float*)d_out;

    char* ws = (char*)d_ws;
    short*    qp  = (short*)(ws);                          // [8192][12][64] bf16
    short*    kp  = (short*)(ws + 12582912);
    short*    vp  = (short*)(ws + 25165824);
    _Float16* att = (_Float16*)(ws + 37748736);            // [8192][768] fp16
    _Float16* xh  = (_Float16*)(ws + 50331648);            // [8192][768] fp16
    _Float16* wqh = (_Float16*)(ws + 62914560);            // [2304][768] fp16
    _Float16* wph = (_Float16*)(ws + 66453504);            // [768][768] fp16

    // 0) fp32 -> fp16 planes
    f32_to_f16_k<<<(BN * Cc / 8 + 255) / 256, 256, 0, stream>>>(x, xh, BN * Cc / 8);
    f32_to_f16_k<<<(C3 * Cc / 8 + 255) / 256, 256, 0, stream>>>(qkv_w, wqh, C3 * Cc / 8);
    f32_to_f16_k<<<(Cc * Cc / 8 + 255) / 256, 256, 0, stream>>>(proj_w, wph, Cc * Cc / 8);
    // 1) QKV GEMM + bias + fused LN -> bf16 q/k/v planes
    gemm_f16<1><<<dim3(C3 / 128, BN / 128), 256, 0, stream>>>(
        xh, wqh, qkv_b, nullptr, qp, kp, vp, qn_g, qn_b, kn_g, kn_b);
    // 2) flash attention -> fp16 att
    flash_attn_mfma<<<Bz * Hh * 8, 256, 0, stream>>>(qp, kp, vp, att);
    // 3) output projection + bias -> fp32 out
    gemm_f16<0><<<dim3(Cc / 128, BN / 128), 256, 0, stream>>>(
        att, wph, proj_b, out, nullptr, nullptr, nullptr, nullptr, nullptr, nullptr, nullptr);
}

// Round 4
// 179.930 us; speedup vs baseline: 6.1056x; 1.0227x over previous
//
#include <hip/hip_runtime.h>
#include <cstdint>

#define Bz 8
#define Nn 1024
#define Cc 768
#define Hh 12
#define Dd 64
#define C3 2304
#define BN 8192

constexpr float EPS = 1e-5f;
// q scale folded with log2(e): softmax exp(S) == exp2(S*log2e), fold into q
constexpr float QSCALE = 0.125f * 1.44269504088896340736f;

typedef __attribute__((ext_vector_type(8))) short bf16x8;
typedef _Float16 f16x8 __attribute__((ext_vector_type(8)));
typedef __attribute__((ext_vector_type(4))) float f32x4;

__device__ __forceinline__ short f2b(float f) {
    union { float f; unsigned u; } x; x.f = f;
    unsigned r = x.u + 0x7FFFu + ((x.u >> 16) & 1u);   // RNE to bf16
    return (short)(r >> 16);
}

__device__ __forceinline__ f32x4 MFMAB(bf16x8 a, bf16x8 b, f32x4 c) {
    return __builtin_amdgcn_mfma_f32_16x16x32_bf16(a, b, c, 0, 0, 0);
}
__device__ __forceinline__ f32x4 MFMAH(f16x8 a, f16x8 b, f32x4 c) {
    return __builtin_amdgcn_mfma_f32_16x16x32_f16(a, b, c, 0, 0, 0);
}
// async global->LDS, 16B per lane; lds dst is wave-uniform base (+lane*16 by HW)
__device__ __forceinline__ void gld16(const void* g, void* l) {
    __builtin_amdgcn_global_load_lds((const __attribute__((address_space(1))) unsigned int*)g,
                                     (__attribute__((address_space(3))) unsigned int*)(l),
                                     16, 0, 0);
}

// ---------------- fp32 -> fp16 convert (8 elems/thread) ----------------
__global__ __launch_bounds__(256) void f32_to_f16_k(const float* __restrict__ s,
                                                    _Float16* __restrict__ d, int n8)
{
    int i = blockIdx.x * 256 + threadIdx.x;
    if (i >= n8) return;
    float4 a = *(const float4*)(s + (size_t)i * 8);
    float4 b = *(const float4*)(s + (size_t)i * 8 + 4);
    f16x8 o;
    o[0] = (_Float16)a.x; o[1] = (_Float16)a.y; o[2] = (_Float16)a.z; o[3] = (_Float16)a.w;
    o[4] = (_Float16)b.x; o[5] = (_Float16)b.y; o[6] = (_Float16)b.z; o[7] = (_Float16)b.w;
    *(f16x8*)(d + (size_t)i * 8) = o;
}

// ---------------- fp16 MFMA GEMM NT: Out[m,n] = sum_k A[m,k]*W[n,k] + bias[n] ----------------
// EPI=0: fp32 out + bias (proj). EPI=1: bias + LN fused, q scaled by QSCALE,
//        write bf16 planes qp/kp/vp [M][12][64].
template<int EPI>
__global__ __launch_bounds__(256) void gemm_f16(
    const _Float16* __restrict__ A,
    const _Float16* __restrict__ W,
    const float* __restrict__ bias,
    float* __restrict__ Out,
    short* __restrict__ qp, short* __restrict__ kp, short* __restrict__ vp,
    const float* __restrict__ qg, const float* __restrict__ qb,
    const float* __restrict__ kg, const float* __restrict__ kb)
{
    __shared__ _Float16 As[128 * 64];   // [row][64k], 128B rows, slot-swizzled
    __shared__ _Float16 Bs[128 * 64];
    const int tid = threadIdx.x;
    const int lane = tid & 63;
    const int w = tid >> 6;
    const int wr = w >> 1, wc = w & 1;
    const int l15 = lane & 15, l4 = lane >> 4;
    const int m0 = blockIdx.y * 128;
    const int n0 = blockIdx.x * 128;
    const int lr = lane >> 3;        // row within an 8-row issue
    const int lslot = lane & 7;      // 16B slot within 128B row

    f32x4 acc[4][4];
#pragma unroll
    for (int mi = 0; mi < 4; ++mi)
#pragma unroll
        for (int ni = 0; ni < 4; ++ni) { acc[mi][ni][0]=0.f; acc[mi][ni][1]=0.f; acc[mi][ni][2]=0.f; acc[mi][ni][3]=0.f; }

    for (int kt = 0; kt < 12; ++kt) {
        const int k0 = kt * 64;
#pragma unroll
        for (int j = 0; j < 8; ++j) {
            int i = w * 8 + j;
            int isA = (i < 16);
            int ib = isA ? i : i - 16;
            int row = ib * 8 + lr;
            int gslot = lslot ^ (row & 7);
            const _Float16* src = (isA ? A + (size_t)(m0 + row) * 768
                                       : W + (size_t)(n0 + row) * 768) + k0 + gslot * 8;
            _Float16* dst = (isA ? As : Bs) + ib * 512;
            gld16(src, dst);
        }
        __syncthreads();
#pragma unroll
        for (int ks = 0; ks < 2; ++ks) {
            f16x8 af[4], bfr[4];
#pragma unroll
            for (int mi = 0; mi < 4; ++mi) {
                int row = wr * 64 + mi * 16 + l15;
                int slot = (ks * 4 + l4) ^ (row & 7);
                af[mi] = *(const f16x8*)&As[row * 64 + slot * 8];
            }
#pragma unroll
            for (int ni = 0; ni < 4; ++ni) {
                int row = wc * 64 + ni * 16 + l15;
                int slot = (ks * 4 + l4) ^ (row & 7);
                bfr[ni] = *(const f16x8*)&Bs[row * 64 + slot * 8];
            }
#pragma unroll
            for (int mi = 0; mi < 4; ++mi)
#pragma unroll
                for (int ni = 0; ni < 4; ++ni)
                    acc[mi][ni] = MFMAH(af[mi], bfr[ni], acc[mi][ni]);
        }
        __syncthreads();
    }

    if (EPI == 0) {
#pragma unroll
        for (int mi = 0; mi < 4; ++mi)
#pragma unroll
            for (int r = 0; r < 4; ++r) {
                int row = m0 + wr * 64 + mi * 16 + l4 * 4 + r;
#pragma unroll
                for (int ni = 0; ni < 4; ++ni) {
                    int col = n0 + wc * 64 + ni * 16 + l15;
                    Out[(size_t)row * Cc + col] = acc[mi][ni][r] + bias[col];
                }
            }
    } else {
        const int ncol0 = n0 + wc * 64;
        const int type = ncol0 / Cc;           // 0=q 1=k 2=v
        const int h = (ncol0 % Cc) >> 6;
        const float* gptr = (type == 0) ? qg : kg;
        const float* bptr = (type == 0) ? qb : kb;
        float biasv[4], gv[4], bv[4];
#pragma unroll
        for (int ni = 0; ni < 4; ++ni) {
            int d = ni * 16 + l15;
            biasv[ni] = bias[ncol0 + d];
            if (type < 2) { gv[ni] = gptr[d]; bv[ni] = bptr[d]; }
        }
        short* plane = (type == 0) ? qp : (type == 1) ? kp : vp;
#pragma unroll
        for (int mi = 0; mi < 4; ++mi)
#pragma unroll
            for (int r = 0; r < 4; ++r) {
                float v[4];
#pragma unroll
                for (int ni = 0; ni < 4; ++ni) v[ni] = acc[mi][ni][r] + biasv[ni];
                int row = m0 + wr * 64 + mi * 16 + l4 * 4 + r;
                size_t base = ((size_t)row * Hh + h) * 64;
                if (type < 2) {
                    float s = v[0] + v[1] + v[2] + v[3];
#pragma unroll
                    for (int off = 1; off < 16; off <<= 1) s += __shfl_xor(s, off);
                    float mu = s * (1.0f / 64.0f);
                    float s2 = 0.f;
#pragma unroll
                    for (int ni = 0; ni < 4; ++ni) { float dv = v[ni] - mu; s2 += dv * dv; }
#pragma unroll
                    for (int off = 1; off < 16; off <<= 1) s2 += __shfl_xor(s2, off);
                    float inv = rsqrtf(s2 * (1.0f / 64.0f) + EPS);
#pragma unroll
                    for (int ni = 0; ni < 4; ++ni) {
                        float rr = (v[ni] - mu) * inv * gv[ni] + bv[ni];
                        if (type == 0) rr *= QSCALE;
                        plane[base + ni * 16 + l15] = f2b(rr);
                    }
                } else {
#pragma unroll
                    for (int ni = 0; ni < 4; ++ni)
                        plane[base + ni * 16 + l15] = f2b(v[ni]);
                }
            }
    }
}

// ---------------- Flash attention, bf16 MFMA, no-max softmax (exp2), K/V double-buffered ----
__global__ __launch_bounds__(256) void flash_attn_mfma(
    const short* __restrict__ qp, const short* __restrict__ kp, const short* __restrict__ vp,
    _Float16* __restrict__ att)
{
    __shared__ short qpl[128 * 64];      // Q tile, then per-wave P rows
    __shared__ short kls[2][64 * 64];    // K tile [k][d] swizzled, double-buffered
    __shared__ short vtl[2][64 * 64];    // V^T tile [d][k] swizzled, double-buffered
    const int tid = threadIdx.x;
    const int lane = tid & 63;
    const int w = tid >> 6;
    const int l15 = lane & 15, l4 = lane >> 4;
    const int lr = lane >> 3, lslot = lane & 7;
    // XCD-aware swizzle: 768 blocks = 8 XCD * 96; same-head q-tiles land on one XCD
    const int bid = (blockIdx.x & 7) * 96 + (blockIdx.x >> 3);
    const int qt = bid & 7;
    const int bh = bid >> 3;
    const int h = bh % Hh;
    const int b = bh / Hh;
    const int q0 = qt * 128;
    const size_t hbase = ((size_t)b * Nn * Hh + h) * 64;   // + seq*768

    // stage Q (128x64 bf16) via global_load_lds, source pre-swizzled
#pragma unroll
    for (int j = 0; j < 4; ++j) {
        int i = w * 4 + j;
        int row = i * 8 + lr;
        int gslot = lslot ^ (row & 7);
        gld16(qp + hbase + (size_t)(q0 + row) * 768 + gslot * 8, &qpl[i * 512]);
    }
    // stage K/V tile 0 into buffer 0
#pragma unroll
    for (int j = 0; j < 2; ++j) {
        int i = w * 2 + j;
        int row = i * 8 + lr;
        int gslot = lslot ^ (row & 7);
        gld16(kp + hbase + (size_t)row * 768 + gslot * 8, &kls[0][i * 512]);
    }
    {
        int n0v = (tid & 31) * 2, d0 = (tid >> 5) * 8;
        const short* s0 = vp + hbase + (size_t)n0v * 768 + d0;
        bf16x8 a0 = *(const bf16x8*)s0;
        bf16x8 a1 = *(const bf16x8*)(s0 + 768);
#pragma unroll
        for (int j = 0; j < 8; ++j) {
            int d = d0 + j;
            unsigned pk = (unsigned short)a0[j] | ((unsigned)(unsigned short)a1[j] << 16);
            *(unsigned*)&vtl[0][d * 64 + (n0v ^ ((d & 7) << 3))] = pk;
        }
    }
    __syncthreads();
    bf16x8 qf[2][2];
#pragma unroll
    for (int mt = 0; mt < 2; ++mt)
#pragma unroll
        for (int ks = 0; ks < 2; ++ks) {
            int r = w * 32 + mt * 16 + l15;
            qf[mt][ks] = *(bf16x8*)&qpl[r * 64 + ((ks * 32 + l4 * 8) ^ ((r & 7) << 3))];
        }

    f32x4 o[2][4];
    float lrun[2][4];
#pragma unroll
    for (int mt = 0; mt < 2; ++mt)
#pragma unroll
        for (int nt = 0; nt < 4; ++nt) { o[mt][nt][0]=0.f; o[mt][nt][1]=0.f; o[mt][nt][2]=0.f; o[mt][nt][3]=0.f; }
#pragma unroll
    for (int mt = 0; mt < 2; ++mt)
#pragma unroll
        for (int r = 0; r < 4; ++r) lrun[mt][r] = 0.f;

    for (int kt = 0; kt < 16; ++kt) {
        const int cur = kt & 1, nxt = cur ^ 1;
        // prefetch next K/V tile into the other buffer (T3 2-phase)
        if (kt < 15) {
#pragma unroll
            for (int j = 0; j < 2; ++j) {
                int i = w * 2 + j;
                int row = i * 8 + lr;
                int gslot = lslot ^ (row & 7);
                gld16(kp + hbase + (size_t)((kt + 1) * 64 + row) * 768 + gslot * 8,
                      &kls[nxt][i * 512]);
            }
            int n0v = (tid & 31) * 2, d0 = (tid >> 5) * 8;
            const short* s0 = vp + hbase + (size_t)((kt + 1) * 64 + n0v) * 768 + d0;
            bf16x8 a0 = *(const bf16x8*)s0;
            bf16x8 a1 = *(const bf16x8*)(s0 + 768);
#pragma unroll
            for (int j = 0; j < 8; ++j) {
                int d = d0 + j;
                unsigned pk = (unsigned short)a0[j] | ((unsigned)(unsigned short)a1[j] << 16);
                *(unsigned*)&vtl[nxt][d * 64 + (n0v ^ ((d & 7) << 3))] = pk;
            }
        }
        // S = Q K^T (logits already scaled by log2e via q)
        f32x4 s[2][4];
#pragma unroll
        for (int nt = 0; nt < 4; ++nt) {
            int r = nt * 16 + l15;
            bf16x8 kf0 = *(bf16x8*)&kls[cur][r * 64 + ((l4 * 8) ^ ((r & 7) << 3))];
            bf16x8 kf1 = *(bf16x8*)&kls[cur][r * 64 + ((32 + l4 * 8) ^ ((r & 7) << 3))];
#pragma unroll
            for (int mt = 0; mt < 2; ++mt) {
                f32x4 a; a[0]=0.f; a[1]=0.f; a[2]=0.f; a[3]=0.f;
                a = MFMAB(qf[mt][0], kf0, a);
                a = MFMAB(qf[mt][1], kf1, a);
                s[mt][nt] = a;
            }
        }
        // no-max softmax: P = exp2(S), accumulate per-thread partial row sums
#pragma unroll
        for (int mt = 0; mt < 2; ++mt)
#pragma unroll
            for (int r = 0; r < 4; ++r) {
                float p0 = exp2f(s[mt][0][r]);
                float p1 = exp2f(s[mt][1][r]);
                float p2 = exp2f(s[mt][2][r]);
                float p3 = exp2f(s[mt][3][r]);
                s[mt][0][r] = p0; s[mt][1][r] = p1; s[mt][2][r] = p2; s[mt][3][r] = p3;
                lrun[mt][r] += (p0 + p1) + (p2 + p3);
            }
        // P -> wave-private rows of qpl (bf16)
#pragma unroll
        for (int mt = 0; mt < 2; ++mt)
#pragma unroll
            for (int r = 0; r < 4; ++r) {
                int row = w * 32 + mt * 16 + l4 * 4 + r;
#pragma unroll
                for (int nt = 0; nt < 4; ++nt)
                    qpl[row * 64 + ((nt * 16 + l15) ^ ((row & 7) << 3))] = f2b(s[mt][nt][r]);
            }
        // O += P V
#pragma unroll
        for (int ks = 0; ks < 2; ++ks) {
            bf16x8 pf[2];
#pragma unroll
            for (int mt = 0; mt < 2; ++mt) {
                int row = w * 32 + mt * 16 + l15;
                pf[mt] = *(bf16x8*)&qpl[row * 64 + ((ks * 32 + l4 * 8) ^ ((row & 7) << 3))];
            }
#pragma unroll
            for (int nt = 0; nt < 4; ++nt) {
                int d = nt * 16 + l15;
                bf16x8 vf = *(bf16x8*)&vtl[cur][d * 64 + ((ks * 32 + l4 * 8) ^ ((d & 7) << 3))];
#pragma unroll
                for (int mt = 0; mt < 2; ++mt)
                    o[mt][nt] = MFMAB(pf[mt], vf, o[mt][nt]);
            }
        }
        __syncthreads();   // drains prefetch gld + V ds_writes; all waves done with cur
    }
    // epilogue: single deferred row-sum reduce, then O /= l, write fp16 att
#pragma unroll
    for (int mt = 0; mt < 2; ++mt)
#pragma unroll
        for (int r = 0; r < 4; ++r) {
            float t = lrun[mt][r];
#pragma unroll
            for (int off = 1; off < 16; off <<= 1) t += __shfl_xor(t, off);
            float inv = 1.0f / t;
            int row = q0 + w * 32 + mt * 16 + l4 * 4 + r;
            _Float16* dst = att + (size_t)(b * Nn + row) * Cc + h * 64 + l15;
#pragma unroll
            for (int nt = 0; nt < 4; ++nt)
                dst[nt * 16] = (_Float16)(o[mt][nt][r] * inv);
        }
}

extern "C" void kernel_launch(void* const* d_in, const int* in_sizes, int n_in,
                              void* d_out, int out_size, void* d_ws, size_t ws_size,
                              hipStream_t stream)
{
    const float* x      = (const float*)d_in[0];
    const float* qkv_w  = (const float*)d_in[1];
    const float* qkv_b  = (const float*)d_in[2];
    const float* qn_g   = (const float*)d_in[3];
    const float* qn_b   = (const float*)d_in[4];
    const float* kn_g   = (const float*)d_in[5];
    const float* kn_b   = (const float*)d_in[6];
    const float* proj_w = (const float*)d_in[7];
    const float* proj_b = (const float*)d_in[8];
    float* out = (float*)d_out;

    char* ws = (char*)d_ws;
    short*    qp  = (short*)(ws);                          // [8192][12][64] bf16
    short*    kp  = (short*)(ws + 12582912);
    short*    vp  = (short*)(ws + 25165824);
    _Float16* att = (_Float16*)(ws + 37748736);            // [8192][768] fp16
    _Float16* xh  = (_Float16*)(ws + 50331648);            // [8192][768] fp16
    _Float16* wqh = (_Float16*)(ws + 62914560);            // [2304][768] fp16
    _Float16* wph = (_Float16*)(ws + 66453504);            // [768][768] fp16

    // 0) fp32 -> fp16 planes
    f32_to_f16_k<<<(BN * Cc / 8 + 255) / 256, 256, 0, stream>>>(x, xh, BN * Cc / 8);
    f32_to_f16_k<<<(C3 * Cc / 8 + 255) / 256, 256, 0, stream>>>(qkv_w, wqh, C3 * Cc / 8);
    f32_to_f16_k<<<(Cc * Cc / 8 + 255) / 256, 256, 0, stream>>>(proj_w, wph, Cc * Cc / 8);
    // 1) QKV GEMM + bias + fused LN (q scaled by 0.125*log2e) -> bf16 q/k/v planes
    gemm_f16<1><<<dim3(C3 / 128, BN / 128), 256, 0, stream>>>(
        xh, wqh, qkv_b, nullptr, qp, kp, vp, qn_g, qn_b, kn_g, kn_b);
    // 2) flash attention -> fp16 att
    flash_attn_mfma<<<Bz * Hh * 8, 256, 0, stream>>>(qp, kp, vp, att);
    // 3) output projection + bias -> fp32 out
    gemm_f16<0><<<dim3(Cc / 128, BN / 128), 256, 0, stream>>>(
        att, wph, proj_b, out, nullptr, nullptr, nullptr, nullptr, nullptr, nullptr, nullptr);
}

// Round 5
// 144.461 us; speedup vs baseline: 7.6046x; 1.2455x over previous
//
#include <hip/hip_runtime.h>
#include <cstdint>

#define Bz 8
#define Nn 1024
#define Cc 768
#define Hh 12
#define Dd 64
#define C3 2304
#define BN 8192

constexpr float EPS = 1e-5f;
// q scale folded with log2(e): softmax exp(S) == exp2(S*log2e), fold into q
constexpr float QSCALE = 0.125f * 1.44269504088896340736f;

typedef __attribute__((ext_vector_type(8))) short bf16x8;
typedef __attribute__((ext_vector_type(4))) short bf16x4;
typedef _Float16 f16x8 __attribute__((ext_vector_type(8)));
typedef __attribute__((ext_vector_type(4))) float f32x4;

__device__ __forceinline__ short f2b(float f) {
    union { float f; unsigned u; } x; x.f = f;
    unsigned r = x.u + 0x7FFFu + ((x.u >> 16) & 1u);   // RNE to bf16
    return (short)(r >> 16);
}
__device__ __forceinline__ short f2bf(float f) {       // round-half-up, 2 VALU ops
    union { float f; unsigned u; } x; x.f = f;
    return (short)((x.u + 0x8000u) >> 16);
}

__device__ __forceinline__ f32x4 MFMAB(bf16x8 a, bf16x8 b, f32x4 c) {
    return __builtin_amdgcn_mfma_f32_16x16x32_bf16(a, b, c, 0, 0, 0);
}
__device__ __forceinline__ f16x8 ldf16(const _Float16* p) { return *(const f16x8*)p; }
__device__ __forceinline__ f32x4 MFMAH(f16x8 a, f16x8 b, f32x4 c) {
    return __builtin_amdgcn_mfma_f32_16x16x32_f16(a, b, c, 0, 0, 0);
}
// async global->LDS, 16B per lane; lds dst is wave-uniform base (+lane*16 by HW)
__device__ __forceinline__ void gld16(const void* g, void* l) {
    __builtin_amdgcn_global_load_lds((const __attribute__((address_space(1))) unsigned int*)g,
                                     (__attribute__((address_space(3))) unsigned int*)(l),
                                     16, 0, 0);
}

// ---------------- fused fp32 -> fp16 convert of x, qkv_w, proj_w ----------------
__global__ __launch_bounds__(256) void cvt_all(
    const float* __restrict__ x, const float* __restrict__ wq, const float* __restrict__ wp,
    _Float16* __restrict__ xh, _Float16* __restrict__ wqh, _Float16* __restrict__ wph)
{
    const int n1 = BN * Cc / 8, n2 = n1 + C3 * Cc / 8, n3 = n2 + Cc * Cc / 8;
    int i = blockIdx.x * 256 + threadIdx.x;
    const float* s; _Float16* d; int off;
    if (i < n1)      { s = x;  d = xh;  off = i; }
    else if (i < n2) { s = wq; d = wqh; off = i - n1; }
    else if (i < n3) { s = wp; d = wph; off = i - n2; }
    else return;
    float4 a = *(const float4*)(s + (size_t)off * 8);
    float4 b = *(const float4*)(s + (size_t)off * 8 + 4);
    f16x8 o;
    o[0] = (_Float16)a.x; o[1] = (_Float16)a.y; o[2] = (_Float16)a.z; o[3] = (_Float16)a.w;
    o[4] = (_Float16)b.x; o[5] = (_Float16)b.y; o[6] = (_Float16)b.z; o[7] = (_Float16)b.w;
    *(f16x8*)(d + (size_t)off * 8) = o;
}

// ---------------- fp16 MFMA GEMM NT: Out[m,n] = sum_k A[m,k]*W[n,k] + bias[n] ----------------
// EPI=0: fp32 out + bias (proj). EPI=1: bias + LN fused, q scaled by QSCALE,
//        write bf16 planes qp/kp/vp [M][12][64].
template<int EPI>
__global__ __launch_bounds__(256) void gemm_f16(
    const _Float16* __restrict__ A,
    const _Float16* __restrict__ W,
    const float* __restrict__ bias,
    float* __restrict__ Out,
    short* __restrict__ qp, short* __restrict__ kp, short* __restrict__ vp,
    const float* __restrict__ qg, const float* __restrict__ qb,
    const float* __restrict__ kg, const float* __restrict__ kb)
{
    __shared__ _Float16 As[128 * 64];   // [row][64k], 128B rows, slot-swizzled
    __shared__ _Float16 Bs[128 * 64];
    const int tid = threadIdx.x;
    const int lane = tid & 63;
    const int w = tid >> 6;
    const int wr = w >> 1, wc = w & 1;
    const int l15 = lane & 15, l4 = lane >> 4;
    const int m0 = blockIdx.y * 128;
    const int n0 = blockIdx.x * 128;
    const int lr = lane >> 3;        // row within an 8-row issue
    const int lslot = lane & 7;      // 16B slot within 128B row

    f32x4 acc[4][4];
#pragma unroll
    for (int mi = 0; mi < 4; ++mi)
#pragma unroll
        for (int ni = 0; ni < 4; ++ni) { acc[mi][ni][0]=0.f; acc[mi][ni][1]=0.f; acc[mi][ni][2]=0.f; acc[mi][ni][3]=0.f; }

    for (int kt = 0; kt < 12; ++kt) {
        const int k0 = kt * 64;
#pragma unroll
        for (int j = 0; j < 8; ++j) {
            int i = w * 8 + j;
            int isA = (i < 16);
            int ib = isA ? i : i - 16;
            int row = ib * 8 + lr;
            int gslot = lslot ^ (row & 7);
            const _Float16* src = (isA ? A + (size_t)(m0 + row) * 768
                                       : W + (size_t)(n0 + row) * 768) + k0 + gslot * 8;
            _Float16* dst = (isA ? As : Bs) + ib * 512;
            gld16(src, dst);
        }
        __syncthreads();
#pragma unroll
        for (int ks = 0; ks < 2; ++ks) {
            f16x8 af[4], bfr[4];
#pragma unroll
            for (int mi = 0; mi < 4; ++mi) {
                int row = wr * 64 + mi * 16 + l15;
                int slot = (ks * 4 + l4) ^ (row & 7);
                af[mi] = ldf16(&As[row * 64 + slot * 8]);
            }
#pragma unroll
            for (int ni = 0; ni < 4; ++ni) {
                int row = wc * 64 + ni * 16 + l15;
                int slot = (ks * 4 + l4) ^ (row & 7);
                bfr[ni] = ldf16(&Bs[row * 64 + slot * 8]);
            }
#pragma unroll
            for (int mi = 0; mi < 4; ++mi)
#pragma unroll
                for (int ni = 0; ni < 4; ++ni)
                    acc[mi][ni] = MFMAH(af[mi], bfr[ni], acc[mi][ni]);
        }
        __syncthreads();
    }

    if (EPI == 0) {
#pragma unroll
        for (int mi = 0; mi < 4; ++mi)
#pragma unroll
            for (int r = 0; r < 4; ++r) {
                int row = m0 + wr * 64 + mi * 16 + l4 * 4 + r;
#pragma unroll
                for (int ni = 0; ni < 4; ++ni) {
                    int col = n0 + wc * 64 + ni * 16 + l15;
                    Out[(size_t)row * Cc + col] = acc[mi][ni][r] + bias[col];
                }
            }
    } else {
        const int ncol0 = n0 + wc * 64;
        const int type = ncol0 / Cc;           // 0=q 1=k 2=v
        const int h = (ncol0 % Cc) >> 6;
        const float* gptr = (type == 0) ? qg : kg;
        const float* bptr = (type == 0) ? qb : kb;
        float biasv[4], gv[4], bv[4];
#pragma unroll
        for (int ni = 0; ni < 4; ++ni) {
            int d = ni * 16 + l15;
            biasv[ni] = bias[ncol0 + d];
            if (type < 2) { gv[ni] = gptr[d]; bv[ni] = bptr[d]; }
        }
        short* plane = (type == 0) ? qp : (type == 1) ? kp : vp;
#pragma unroll
        for (int mi = 0; mi < 4; ++mi)
#pragma unroll
            for (int r = 0; r < 4; ++r) {
                float v[4];
#pragma unroll
                for (int ni = 0; ni < 4; ++ni) v[ni] = acc[mi][ni][r] + biasv[ni];
                int row = m0 + wr * 64 + mi * 16 + l4 * 4 + r;
                size_t base = ((size_t)row * Hh + h) * 64;
                if (type < 2) {
                    float s = v[0] + v[1] + v[2] + v[3];
#pragma unroll
                    for (int off = 1; off < 16; off <<= 1) s += __shfl_xor(s, off);
                    float mu = s * (1.0f / 64.0f);
                    float s2 = 0.f;
#pragma unroll
                    for (int ni = 0; ni < 4; ++ni) { float dv = v[ni] - mu; s2 += dv * dv; }
#pragma unroll
                    for (int off = 1; off < 16; off <<= 1) s2 += __shfl_xor(s2, off);
                    float inv = rsqrtf(s2 * (1.0f / 64.0f) + EPS);
#pragma unroll
                    for (int ni = 0; ni < 4; ++ni) {
                        float rr = (v[ni] - mu) * inv * gv[ni] + bv[ni];
                        if (type == 0) rr *= QSCALE;
                        plane[base + ni * 16 + l15] = f2b(rr);
                    }
                } else {
#pragma unroll
                    for (int ni = 0; ni < 4; ++ni)
                        plane[base + ni * 16 + l15] = f2b(v[ni]);
                }
            }
    }
}

// ---------------- Flash attention: 8 waves x 16 q-rows, no-max softmax, K/V dbuf ----------------
__global__ __launch_bounds__(512, 4) void flash_attn_mfma(
    const short* __restrict__ qp, const short* __restrict__ kp, const short* __restrict__ vp,
    _Float16* __restrict__ att)
{
    __shared__ short ppl[128 * 64];      // per-wave P rows (wave w owns rows w*16..w*16+15)
    __shared__ short kls[2][64 * 64];    // K tile [k][d] swizzled, double-buffered
    __shared__ short vtl[2][64 * 64];    // V^T tile [d][k] swizzled, double-buffered
    const int tid = threadIdx.x;
    const int lane = tid & 63;
    const int w = tid >> 6;              // 0..7
    const int l15 = lane & 15, l4 = lane >> 4;
    const int lr = lane >> 3, lslot = lane & 7;
    // XCD-aware swizzle: 768 blocks = 8 XCD * 96; same-head q-tiles share one XCD's L2
    const int bid = (blockIdx.x & 7) * 96 + (blockIdx.x >> 3);
    const int qt = bid & 7;
    const int bh = bid >> 3;
    const int h = bh % Hh;
    const int b = bh / Hh;
    const int q0 = qt * 128;
    const size_t hbase = ((size_t)b * Nn * Hh + h) * 64;   // + seq*768

    // Q fragments straight from global (one-time, L2/L3-resident)
    bf16x8 qf[2];
    {
        const short* qsrc = qp + hbase + (size_t)(q0 + w * 16 + l15) * 768;
        qf[0] = *(const bf16x8*)(qsrc + l4 * 8);
        qf[1] = *(const bf16x8*)(qsrc + 32 + l4 * 8);
    }
    // stage K tile 0 (8 issues, one per wave)
    {
        int row = w * 8 + lr;
        int gslot = lslot ^ (row & 7);
        gld16(kp + hbase + (size_t)row * 768 + gslot * 8, &kls[0][w * 512]);
    }
    // stage V tile 0 transposed: thread -> krows n0v,n0v+1 x d d0..d0+3
    {
        int n0v = (tid & 31) * 2, d0 = (tid >> 5) * 4;
        const short* s0 = vp + hbase + (size_t)n0v * 768 + d0;
        bf16x4 a0 = *(const bf16x4*)s0;
        bf16x4 a1 = *(const bf16x4*)(s0 + 768);
#pragma unroll
        for (int j = 0; j < 4; ++j) {
            int d = d0 + j;
            unsigned pk = (unsigned short)a0[j] | ((unsigned)(unsigned short)a1[j] << 16);
            *(unsigned*)&vtl[0][d * 64 + (n0v ^ ((d & 7) << 3))] = pk;
        }
    }
    __syncthreads();

    f32x4 o[4];
    float lrun[4];
#pragma unroll
    for (int nt = 0; nt < 4; ++nt) { o[nt][0]=0.f; o[nt][1]=0.f; o[nt][2]=0.f; o[nt][3]=0.f; }
#pragma unroll
    for (int r = 0; r < 4; ++r) lrun[r] = 0.f;

    for (int kt = 0; kt < 16; ++kt) {
        const int cur = kt & 1, nxt = cur ^ 1;
        // T14 split: issue next-tile loads now (K direct to LDS, V to regs)
        bf16x4 va0, va1;
        if (kt < 15) {
            int row = w * 8 + lr;
            int gslot = lslot ^ (row & 7);
            gld16(kp + hbase + (size_t)((kt + 1) * 64 + row) * 768 + gslot * 8,
                  &kls[nxt][w * 512]);
            int n0v = (tid & 31) * 2, d0 = (tid >> 5) * 4;
            const short* s0 = vp + hbase + (size_t)((kt + 1) * 64 + n0v) * 768 + d0;
            va0 = *(const bf16x4*)s0;
            va1 = *(const bf16x4*)(s0 + 768);
        }
        // S = Q K^T (logits pre-scaled by log2e via q)
        f32x4 s[4];
        __builtin_amdgcn_s_setprio(1);
#pragma unroll
        for (int nt = 0; nt < 4; ++nt) {
            int r = nt * 16 + l15;
            bf16x8 kf0 = *(bf16x8*)&kls[cur][r * 64 + ((l4 * 8) ^ ((r & 7) << 3))];
            bf16x8 kf1 = *(bf16x8*)&kls[cur][r * 64 + ((32 + l4 * 8) ^ ((r & 7) << 3))];
            f32x4 a; a[0]=0.f; a[1]=0.f; a[2]=0.f; a[3]=0.f;
            a = MFMAB(qf[0], kf0, a);
            a = MFMAB(qf[1], kf1, a);
            s[nt] = a;
        }
        __builtin_amdgcn_s_setprio(0);
        // no-max softmax: P = exp2(S); partial row sums stay per-thread
#pragma unroll
        for (int r = 0; r < 4; ++r) {
            float p0 = exp2f(s[0][r]);
            float p1 = exp2f(s[1][r]);
            float p2 = exp2f(s[2][r]);
            float p3 = exp2f(s[3][r]);
            lrun[r] += (p0 + p1) + (p2 + p3);
            int row = w * 16 + l4 * 4 + r;
            int rs = row * 64, sw = (row & 7) << 3;
            ppl[rs + ((l15) ^ sw)]      = f2bf(p0);
            ppl[rs + ((16 + l15) ^ sw)] = f2bf(p1);
            ppl[rs + ((32 + l15) ^ sw)] = f2bf(p2);
            ppl[rs + ((48 + l15) ^ sw)] = f2bf(p3);
        }
        // O += P V
        {
            int prow = w * 16 + l15;
            int psw = (prow & 7) << 3;
            bf16x8 pf0 = *(bf16x8*)&ppl[prow * 64 + ((l4 * 8) ^ psw)];
            bf16x8 pf1 = *(bf16x8*)&ppl[prow * 64 + ((32 + l4 * 8) ^ psw)];
            __builtin_amdgcn_s_setprio(1);
#pragma unroll
            for (int nt = 0; nt < 4; ++nt) {
                int d = nt * 16 + l15;
                int dsw = (d & 7) << 3;
                bf16x8 vf0 = *(bf16x8*)&vtl[cur][d * 64 + ((l4 * 8) ^ dsw)];
                bf16x8 vf1 = *(bf16x8*)&vtl[cur][d * 64 + ((32 + l4 * 8) ^ dsw)];
                o[nt] = MFMAB(pf0, vf0, o[nt]);
                o[nt] = MFMAB(pf1, vf1, o[nt]);
            }
            __builtin_amdgcn_s_setprio(0);
        }
        // late half of T14: commit prefetched V regs to LDS (other buffer)
        if (kt < 15) {
            int n0v = (tid & 31) * 2, d0 = (tid >> 5) * 4;
#pragma unroll
            for (int j = 0; j < 4; ++j) {
                int d = d0 + j;
                unsigned pk = (unsigned short)va0[j] | ((unsigned)(unsigned short)va1[j] << 16);
                *(unsigned*)&vtl[nxt][d * 64 + (n0v ^ ((d & 7) << 3))] = pk;
            }
        }
        __syncthreads();   // drains K gld + V ds_writes; all waves done with cur
    }
    // epilogue: deferred row-sum reduce, O /= l, write fp16 att
#pragma unroll
    for (int r = 0; r < 4; ++r) {
        float t = lrun[r];
#pragma unroll
        for (int off = 1; off < 16; off <<= 1) t += __shfl_xor(t, off);
        float inv = 1.0f / t;
        int row = q0 + w * 16 + l4 * 4 + r;
        _Float16* dst = att + (size_t)(b * Nn + row) * Cc + h * 64 + l15;
#pragma unroll
        for (int nt = 0; nt < 4; ++nt)
            dst[nt * 16] = (_Float16)(o[nt][r] * inv);
    }
}

extern "C" void kernel_launch(void* const* d_in, const int* in_sizes, int n_in,
                              void* d_out, int out_size, void* d_ws, size_t ws_size,
                              hipStream_t stream)
{
    const float* x      = (const float*)d_in[0];
    const float* qkv_w  = (const float*)d_in[1];
    const float* qkv_b  = (const float*)d_in[2];
    const float* qn_g   = (const float*)d_in[3];
    const float* qn_b   = (const float*)d_in[4];
    const float* kn_g   = (const float*)d_in[5];
    const float* kn_b   = (const float*)d_in[6];
    const float* proj_w = (const float*)d_in[7];
    const float* proj_b = (const float*)d_in[8];
    float* out = (float*)d_out;

    char* ws = (char*)d_ws;
    short*    qp  = (short*)(ws);                          // [8192][12][64] bf16
    short*    kp  = (short*)(ws + 12582912);
    short*    vp  = (short*)(ws + 25165824);
    _Float16* att = (_Float16*)(ws + 37748736);            // [8192][768] fp16
    _Float16* xh  = (_Float16*)(ws + 50331648);            // [8192][768] fp16
    _Float16* wqh = (_Float16*)(ws + 62914560);            // [2304][768] fp16
    _Float16* wph = (_Float16*)(ws + 66453504);            // [768][768] fp16

    // 0) fused fp32 -> fp16 conversions
    {
        const int n3 = BN * Cc / 8 + C3 * Cc / 8 + Cc * Cc / 8;
        cvt_all<<<(n3 + 255) / 256, 256, 0, stream>>>(x, qkv_w, proj_w, xh, wqh, wph);
    }
    // 1) QKV GEMM + bias + fused LN (q scaled by 0.125*log2e) -> bf16 q/k/v planes
    gemm_f16<1><<<dim3(C3 / 128, BN / 128), 256, 0, stream>>>(
        xh, wqh, qkv_b, nullptr, qp, kp, vp, qn_g, qn_b, kn_g, kn_b);
    // 2) flash attention -> fp16 att
    flash_attn_mfma<<<Bz * Hh * 8, 512, 0, stream>>>(qp, kp, vp, att);
    // 3) output projection + bias -> fp32 out
    gemm_f16<0><<<dim3(Cc / 128, BN / 128), 256, 0, stream>>>(
        att, wph, proj_b, out, nullptr, nullptr, nullptr, nullptr, nullptr, nullptr, nullptr);
}

// Round 6
// 133.005 us; speedup vs baseline: 8.2596x; 1.0861x over previous
//
#include <hip/hip_runtime.h>
#include <cstdint>

#define Bz 8
#define Nn 1024
#define Cc 768
#define Hh 12
#define Dd 64
#define C3 2304
#define BN 8192

constexpr float EPS = 1e-5f;
// q scale folded with log2(e): softmax exp(S) == exp2(S*log2e), fold into q
constexpr float QSCALE = 0.125f * 1.44269504088896340736f;

typedef __attribute__((ext_vector_type(8))) short bf16x8;
typedef _Float16 f16x8 __attribute__((ext_vector_type(8)));
typedef __attribute__((ext_vector_type(4))) float f32x4;
typedef __attribute__((ext_vector_type(16))) float f32x16;

__device__ __forceinline__ short f2b(float f) {
    union { float f; unsigned u; } x; x.f = f;
    unsigned r = x.u + 0x7FFFu + ((x.u >> 16) & 1u);   // RNE to bf16
    return (short)(r >> 16);
}
__device__ __forceinline__ unsigned cvtpk(float a, float b) {   // (lo=a, hi=b) bf16 pair, RNE
    unsigned r;
    asm("v_cvt_pk_bf16_f32 %0, %1, %2" : "=v"(r) : "v"(a), "v"(b));
    return r;
}

__device__ __forceinline__ f32x4 MFMAH(f16x8 a, f16x8 b, f32x4 c) {
    return __builtin_amdgcn_mfma_f32_16x16x32_f16(a, b, c, 0, 0, 0);
}
__device__ __forceinline__ f32x16 MFMA32(bf16x8 a, bf16x8 b, f32x16 c) {
    return __builtin_amdgcn_mfma_f32_32x32x16_bf16(a, b, c, 0, 0, 0);
}
__device__ __forceinline__ f16x8 ldf16(const _Float16* p) { return *(const f16x8*)p; }
// async global->LDS, 16B per lane; lds dst is wave-uniform base (+lane*16 by HW)
__device__ __forceinline__ void gld16(const void* g, void* l) {
    __builtin_amdgcn_global_load_lds((const __attribute__((address_space(1))) unsigned int*)g,
                                     (__attribute__((address_space(3))) unsigned int*)(l),
                                     16, 0, 0);
}

// ---------------- fused fp32 -> fp16 convert of x, qkv_w, proj_w ----------------
__global__ __launch_bounds__(256) void cvt_all(
    const float* __restrict__ x, const float* __restrict__ wq, const float* __restrict__ wp,
    _Float16* __restrict__ xh, _Float16* __restrict__ wqh, _Float16* __restrict__ wph)
{
    const int n1 = BN * Cc / 8, n2 = n1 + C3 * Cc / 8, n3 = n2 + Cc * Cc / 8;
    int i = blockIdx.x * 256 + threadIdx.x;
    const float* s; _Float16* d; int off;
    if (i < n1)      { s = x;  d = xh;  off = i; }
    else if (i < n2) { s = wq; d = wqh; off = i - n1; }
    else if (i < n3) { s = wp; d = wph; off = i - n2; }
    else return;
    float4 a = *(const float4*)(s + (size_t)off * 8);
    float4 b = *(const float4*)(s + (size_t)off * 8 + 4);
    f16x8 o;
    o[0] = (_Float16)a.x; o[1] = (_Float16)a.y; o[2] = (_Float16)a.z; o[3] = (_Float16)a.w;
    o[4] = (_Float16)b.x; o[5] = (_Float16)b.y; o[6] = (_Float16)b.z; o[7] = (_Float16)b.w;
    *(f16x8*)(d + (size_t)off * 8) = o;
}

// ---------------- fp16 MFMA GEMM NT: Out[m,n] = sum_k A[m,k]*W[n,k] + bias[n] ----------------
template<int EPI>
__global__ __launch_bounds__(256) void gemm_f16(
    const _Float16* __restrict__ A,
    const _Float16* __restrict__ W,
    const float* __restrict__ bias,
    float* __restrict__ Out,
    short* __restrict__ qp, short* __restrict__ kp, short* __restrict__ vp,
    const float* __restrict__ qg, const float* __restrict__ qb,
    const float* __restrict__ kg, const float* __restrict__ kb)
{
    __shared__ _Float16 As[128 * 64];   // [row][64k], 128B rows, slot-swizzled
    __shared__ _Float16 Bs[128 * 64];
    const int tid = threadIdx.x;
    const int lane = tid & 63;
    const int w = tid >> 6;
    const int wr = w >> 1, wc = w & 1;
    const int l15 = lane & 15, l4 = lane >> 4;
    const int m0 = blockIdx.y * 128;
    const int n0 = blockIdx.x * 128;
    const int lr = lane >> 3;
    const int lslot = lane & 7;

    f32x4 acc[4][4];
#pragma unroll
    for (int mi = 0; mi < 4; ++mi)
#pragma unroll
        for (int ni = 0; ni < 4; ++ni) { acc[mi][ni][0]=0.f; acc[mi][ni][1]=0.f; acc[mi][ni][2]=0.f; acc[mi][ni][3]=0.f; }

    for (int kt = 0; kt < 12; ++kt) {
        const int k0 = kt * 64;
#pragma unroll
        for (int j = 0; j < 8; ++j) {
            int i = w * 8 + j;
            int isA = (i < 16);
            int ib = isA ? i : i - 16;
            int row = ib * 8 + lr;
            int gslot = lslot ^ (row & 7);
            const _Float16* src = (isA ? A + (size_t)(m0 + row) * 768
                                       : W + (size_t)(n0 + row) * 768) + k0 + gslot * 8;
            _Float16* dst = (isA ? As : Bs) + ib * 512;
            gld16(src, dst);
        }
        __syncthreads();
#pragma unroll
        for (int ks = 0; ks < 2; ++ks) {
            f16x8 af[4], bfr[4];
#pragma unroll
            for (int mi = 0; mi < 4; ++mi) {
                int row = wr * 64 + mi * 16 + l15;
                int slot = (ks * 4 + l4) ^ (row & 7);
                af[mi] = ldf16(&As[row * 64 + slot * 8]);
            }
#pragma unroll
            for (int ni = 0; ni < 4; ++ni) {
                int row = wc * 64 + ni * 16 + l15;
                int slot = (ks * 4 + l4) ^ (row & 7);
                bfr[ni] = ldf16(&Bs[row * 64 + slot * 8]);
            }
#pragma unroll
            for (int mi = 0; mi < 4; ++mi)
#pragma unroll
                for (int ni = 0; ni < 4; ++ni)
                    acc[mi][ni] = MFMAH(af[mi], bfr[ni], acc[mi][ni]);
        }
        __syncthreads();
    }

    if (EPI == 0) {
#pragma unroll
        for (int mi = 0; mi < 4; ++mi)
#pragma unroll
            for (int r = 0; r < 4; ++r) {
                int row = m0 + wr * 64 + mi * 16 + l4 * 4 + r;
#pragma unroll
                for (int ni = 0; ni < 4; ++ni) {
                    int col = n0 + wc * 64 + ni * 16 + l15;
                    Out[(size_t)row * Cc + col] = acc[mi][ni][r] + bias[col];
                }
            }
    } else {
        const int ncol0 = n0 + wc * 64;
        const int type = ncol0 / Cc;           // 0=q 1=k 2=v
        const int h = (ncol0 % Cc) >> 6;
        const float* gptr = (type == 0) ? qg : kg;
        const float* bptr = (type == 0) ? qb : kb;
        float biasv[4], gv[4], bv[4];
#pragma unroll
        for (int ni = 0; ni < 4; ++ni) {
            int d = ni * 16 + l15;
            biasv[ni] = bias[ncol0 + d];
            if (type < 2) { gv[ni] = gptr[d]; bv[ni] = bptr[d]; }
        }
        short* plane = (type == 0) ? qp : (type == 1) ? kp : vp;
#pragma unroll
        for (int mi = 0; mi < 4; ++mi)
#pragma unroll
            for (int r = 0; r < 4; ++r) {
                float v[4];
#pragma unroll
                for (int ni = 0; ni < 4; ++ni) v[ni] = acc[mi][ni][r] + biasv[ni];
                int row = m0 + wr * 64 + mi * 16 + l4 * 4 + r;
                size_t base = ((size_t)row * Hh + h) * 64;
                if (type < 2) {
                    float s = v[0] + v[1] + v[2] + v[3];
#pragma unroll
                    for (int off = 1; off < 16; off <<= 1) s += __shfl_xor(s, off);
                    float mu = s * (1.0f / 64.0f);
                    float s2 = 0.f;
#pragma unroll
                    for (int ni = 0; ni < 4; ++ni) { float dv = v[ni] - mu; s2 += dv * dv; }
#pragma unroll
                    for (int off = 1; off < 16; off <<= 1) s2 += __shfl_xor(s2, off);
                    float inv = rsqrtf(s2 * (1.0f / 64.0f) + EPS);
#pragma unroll
                    for (int ni = 0; ni < 4; ++ni) {
                        float rr = (v[ni] - mu) * inv * gv[ni] + bv[ni];
                        if (type == 0) rr *= QSCALE;
                        plane[base + ni * 16 + l15] = f2b(rr);
                    }
                } else {
#pragma unroll
                    for (int ni = 0; ni < 4; ++ni)
                        plane[base + ni * 16 + l15] = f2b(v[ni]);
                }
            }
    }
}

// ---------------- Flash attention: 32x32 MFMA, swapped QK^T, in-register P ----------------
// 4 waves x 32 q-rows = 128 q/block. K/V 64-tiles double-buffered in 32KB LDS.
// S^T = mfma(K,Q) puts each q-row lane-local: softmax is per-lane scalar; P->A-frag
// via cvt_pk_bf16 + shfl_xor(32) (no LDS round trip).
__global__ __launch_bounds__(256, 4) void flash_attn_mfma(
    const short* __restrict__ qp, const short* __restrict__ kp, const short* __restrict__ vp,
    _Float16* __restrict__ att)
{
    __shared__ short kls[2][64 * 64];    // K tile [k][d], 16B-slot XOR swizzle
    __shared__ short vtl[2][64 * 64];    // V^T tile [d][k], same swizzle
    const int tid = threadIdx.x;
    const int lane = tid & 63;
    const int w = tid >> 6;              // 0..3
    const int l31 = lane & 31;
    const int hi = lane >> 5;            // 0/1
    const int lr = lane >> 3;            // 0..7
    const int lslot = lane & 7;
    // XCD-aware swizzle: 768 = 8 XCD * 96 (bijective)
    const int bid = (blockIdx.x & 7) * 96 + (blockIdx.x >> 3);
    const int qt = bid & 7;
    const int bh = bid >> 3;
    const int h = bh % Hh;
    const int b = bh / Hh;
    const int q0 = qt * 128;
    const size_t hbase = ((size_t)b * Nn * Hh + h) * 64;
    const int n0v = (tid & 31) * 2, d0v = (tid >> 5) * 8;

    // Q fragments (B-operand layout): qf[ds] = Q[q=l31][ds*16 + hi*8 .. +7]
    bf16x8 qf[4];
    {
        const short* qsrc = qp + hbase + (size_t)(q0 + w * 32 + l31) * 768 + hi * 8;
#pragma unroll
        for (int ds = 0; ds < 4; ++ds)
            qf[ds] = *(const bf16x8*)(qsrc + ds * 16);
    }

    // prologue: stage K0 + V0
#pragma unroll
    for (int i = 0; i < 2; ++i) {
        int rl = i * 32 + w * 8 + lr;
        gld16(kp + hbase + (size_t)rl * 768 + (lslot ^ lr) * 8,
              &kls[0][(i * 32 + w * 8) * 64]);
    }
    {
        const short* s0 = vp + hbase + (size_t)n0v * 768 + d0v;
        bf16x8 a0 = *(const bf16x8*)s0;
        bf16x8 a1 = *(const bf16x8*)(s0 + 768);
#pragma unroll
        for (int j = 0; j < 8; ++j) {
            int d = d0v + j;
            unsigned pk = (unsigned short)a0[j] | ((unsigned)(unsigned short)a1[j] << 16);
            *(unsigned*)&vtl[0][d * 64 + (((n0v >> 3) ^ (d & 7)) << 3) + (n0v & 7)] = pk;
        }
    }
    __syncthreads();

    f32x16 o0, o1;
#pragma unroll
    for (int i = 0; i < 16; ++i) { o0[i] = 0.f; o1[i] = 0.f; }
    float lrun = 0.f;
    unsigned afu[4][4];

    for (int kt = 0; kt < 16; ++kt) {
        const int cur = kt & 1, nxt = cur ^ 1;
        // T14: issue next K (gld) + load next V to regs now; commit V after PV
        bf16x8 va0, va1;
        if (kt < 15) {
#pragma unroll
            for (int i = 0; i < 2; ++i) {
                int rl = i * 32 + w * 8 + lr;
                gld16(kp + hbase + (size_t)((kt + 1) * 64 + rl) * 768 + (lslot ^ lr) * 8,
                      &kls[nxt][(i * 32 + w * 8) * 64]);
            }
            const short* s0 = vp + hbase + (size_t)((kt + 1) * 64 + n0v) * 768 + d0v;
            va0 = *(const bf16x8*)s0;
            va1 = *(const bf16x8*)(s0 + 768);
        }
        // S^T = mfma(K, Q): lane holds P[k-set][q=l31]; per 32-k tile 16 values
#pragma unroll
        for (int t2 = 0; t2 < 2; ++t2) {
            f32x16 st;
#pragma unroll
            for (int i = 0; i < 16; ++i) st[i] = 0.f;
            const int row = t2 * 32 + l31;
            const int rsw = row & 7;
#pragma unroll
            for (int ds = 0; ds < 4; ++ds) {
                bf16x8 kf = *(const bf16x8*)&kls[cur][row * 64 + (((ds * 2 + hi) ^ rsw) << 3)];
                st = MFMA32(kf, qf[ds], st);
            }
            // exp2 in place + per-lane partial row sum (q = l31 fixed per lane)
#pragma unroll
            for (int i = 0; i < 16; ++i) { st[i] = exp2f(st[i]); lrun += st[i]; }
            // pack pairs (adjacent k) then exchange halves: build PV A-frags in regs
            unsigned pk[8], sx[8];
#pragma unroll
            for (int i = 0; i < 8; ++i) pk[i] = cvtpk(st[2 * i], st[2 * i + 1]);
#pragma unroll
            for (int i = 0; i < 8; ++i) sx[i] = (unsigned)__shfl_xor((int)pk[i], 32);
            afu[t2 * 2 + 0][0] = hi ? sx[2] : pk[0];
            afu[t2 * 2 + 0][1] = hi ? sx[3] : pk[1];
            afu[t2 * 2 + 0][2] = hi ? pk[2] : sx[0];
            afu[t2 * 2 + 0][3] = hi ? pk[3] : sx[1];
            afu[t2 * 2 + 1][0] = hi ? sx[6] : pk[4];
            afu[t2 * 2 + 1][1] = hi ? sx[7] : pk[5];
            afu[t2 * 2 + 1][2] = hi ? pk[6] : sx[4];
            afu[t2 * 2 + 1][3] = hi ? pk[7] : sx[5];
        }
        // O += P V  (two independent d-tiles)
        __builtin_amdgcn_s_setprio(1);
#pragma unroll
        for (int c = 0; c < 4; ++c) {
            union { bf16x8 v; unsigned u[4]; } a;
            a.u[0] = afu[c][0]; a.u[1] = afu[c][1]; a.u[2] = afu[c][2]; a.u[3] = afu[c][3];
            const int r0 = l31, r1 = 32 + l31;
            const int sw = l31 & 7;
            bf16x8 vf0 = *(const bf16x8*)&vtl[cur][r0 * 64 + (((c * 2 + hi) ^ sw) << 3)];
            bf16x8 vf1 = *(const bf16x8*)&vtl[cur][r1 * 64 + (((c * 2 + hi) ^ sw) << 3)];
            o0 = MFMA32(a.v, vf0, o0);
            o1 = MFMA32(a.v, vf1, o1);
        }
        __builtin_amdgcn_s_setprio(0);
        // commit prefetched V to the other buffer
        if (kt < 15) {
#pragma unroll
            for (int j = 0; j < 8; ++j) {
                int d = d0v + j;
                unsigned pk = (unsigned short)va0[j] | ((unsigned)(unsigned short)va1[j] << 16);
                *(unsigned*)&vtl[nxt][d * 64 + (((n0v >> 3) ^ (d & 7)) << 3) + (n0v & 7)] = pk;
            }
        }
        __syncthreads();
    }

    // epilogue: complete row sums across halves, divide, store fp16
    lrun += __shfl_xor(lrun, 32);
    float linv = 1.0f / lrun;            // inv for q = l31
#pragma unroll
    for (int r = 0; r < 16; ++r) {
        int qr = (r & 3) + 8 * (r >> 2) + 4 * hi;
        float invr = __shfl(linv, qr);
        int row = q0 + w * 32 + qr;
        _Float16* dst = att + (size_t)(b * Nn + row) * Cc + h * 64 + l31;
        dst[0]  = (_Float16)(o0[r] * invr);
        dst[32] = (_Float16)(o1[r] * invr);
    }
}

extern "C" void kernel_launch(void* const* d_in, const int* in_sizes, int n_in,
                              void* d_out, int out_size, void* d_ws, size_t ws_size,
                              hipStream_t stream)
{
    const float* x      = (const float*)d_in[0];
    const float* qkv_w  = (const float*)d_in[1];
    const float* qkv_b  = (const float*)d_in[2];
    const float* qn_g   = (const float*)d_in[3];
    const float* qn_b   = (const float*)d_in[4];
    const float* kn_g   = (const float*)d_in[5];
    const float* kn_b   = (const float*)d_in[6];
    const float* proj_w = (const float*)d_in[7];
    const float* proj_b = (const float*)d_in[8];
    float* out = (float*)d_out;

    char* ws = (char*)d_ws;
    short*    qp  = (short*)(ws);                          // [8192][12][64] bf16
    short*    kp  = (short*)(ws + 12582912);
    short*    vp  = (short*)(ws + 25165824);
    _Float16* att = (_Float16*)(ws + 37748736);            // [8192][768] fp16
    _Float16* xh  = (_Float16*)(ws + 50331648);            // [8192][768] fp16
    _Float16* wqh = (_Float16*)(ws + 62914560);            // [2304][768] fp16
    _Float16* wph = (_Float16*)(ws + 66453504);            // [768][768] fp16

    // 0) fused fp32 -> fp16 conversions
    {
        const int n3 = BN * Cc / 8 + C3 * Cc / 8 + Cc * Cc / 8;
        cvt_all<<<(n3 + 255) / 256, 256, 0, stream>>>(x, qkv_w, proj_w, xh, wqh, wph);
    }
    // 1) QKV GEMM + bias + fused LN (q scaled by 0.125*log2e) -> bf16 q/k/v planes
    gemm_f16<1><<<dim3(C3 / 128, BN / 128), 256, 0, stream>>>(
        xh, wqh, qkv_b, nullptr, qp, kp, vp, qn_g, qn_b, kn_g, kn_b);
    // 2) flash attention -> fp16 att
    flash_attn_mfma<<<Bz * Hh * 8, 256, 0, stream>>>(qp, kp, vp, att);
    // 3) output projection + bias -> fp32 out
    gemm_f16<0><<<dim3(Cc / 128, BN / 128), 256, 0, stream>>>(
        att, wph, proj_b, out, nullptr, nullptr, nullptr, nullptr, nullptr, nullptr, nullptr);
}

// Round 7
// 128.032 us; speedup vs baseline: 8.5805x; 1.0388x over previous
//
#include <hip/hip_runtime.h>
#include <cstdint>

#define Bz 8
#define Nn 1024
#define Cc 768
#define Hh 12
#define Dd 64
#define C3 2304
#define BN 8192

constexpr float EPS = 1e-5f;
// q scale folded with log2(e): softmax exp(S) == exp2(S*log2e), fold into q
constexpr float QSCALE = 0.125f * 1.44269504088896340736f;

typedef __attribute__((ext_vector_type(8))) short bf16x8;
typedef _Float16 f16x8 __attribute__((ext_vector_type(8)));
typedef __attribute__((ext_vector_type(4))) float f32x4;
typedef __attribute__((ext_vector_type(16))) float f32x16;

__device__ __forceinline__ short f2b(float f) {
    union { float f; unsigned u; } x; x.f = f;
    unsigned r = x.u + 0x7FFFu + ((x.u >> 16) & 1u);   // RNE to bf16
    return (short)(r >> 16);
}
__device__ __forceinline__ unsigned cvtpk(float a, float b) {   // (lo=a, hi=b) bf16 pair, RNE
    unsigned r;
    asm("v_cvt_pk_bf16_f32 %0, %1, %2" : "=v"(r) : "v"(a), "v"(b));
    return r;
}

__device__ __forceinline__ f32x4 MFMAH(f16x8 a, f16x8 b, f32x4 c) {
    return __builtin_amdgcn_mfma_f32_16x16x32_f16(a, b, c, 0, 0, 0);
}
__device__ __forceinline__ f32x16 MFMA32(bf16x8 a, bf16x8 b, f32x16 c) {
    return __builtin_amdgcn_mfma_f32_32x32x16_bf16(a, b, c, 0, 0, 0);
}
__device__ __forceinline__ f16x8 ldf16(const _Float16* p) { return *(const f16x8*)p; }
// async global->LDS, 16B per lane; lds dst is wave-uniform base (+lane*16 by HW)
__device__ __forceinline__ void gld16(const void* g, void* l) {
    __builtin_amdgcn_global_load_lds((const __attribute__((address_space(1))) unsigned int*)g,
                                     (__attribute__((address_space(3))) unsigned int*)(l),
                                     16, 0, 0);
}

// ---------------- fused fp32 -> fp16 convert of x, qkv_w, proj_w ----------------
__global__ __launch_bounds__(256) void cvt_all(
    const float* __restrict__ x, const float* __restrict__ wq, const float* __restrict__ wp,
    _Float16* __restrict__ xh, _Float16* __restrict__ wqh, _Float16* __restrict__ wph)
{
    const int n1 = BN * Cc / 8, n2 = n1 + C3 * Cc / 8, n3 = n2 + Cc * Cc / 8;
    int i = blockIdx.x * 256 + threadIdx.x;
    const float* s; _Float16* d; int off;
    if (i < n1)      { s = x;  d = xh;  off = i; }
    else if (i < n2) { s = wq; d = wqh; off = i - n1; }
    else if (i < n3) { s = wp; d = wph; off = i - n2; }
    else return;
    float4 a = *(const float4*)(s + (size_t)off * 8);
    float4 b = *(const float4*)(s + (size_t)off * 8 + 4);
    f16x8 o;
    o[0] = (_Float16)a.x; o[1] = (_Float16)a.y; o[2] = (_Float16)a.z; o[3] = (_Float16)a.w;
    o[4] = (_Float16)b.x; o[5] = (_Float16)b.y; o[6] = (_Float16)b.z; o[7] = (_Float16)b.w;
    *(f16x8*)(d + (size_t)off * 8) = o;
}

// ---------------- fp16 MFMA GEMM NT, 2-phase dbuf prefetch + XCD chunking ----------------
// Out[m,n] = sum_k A[m,k]*W[n,k] + bias[n]; K=768 fixed. 1D grid, nx = N/128.
// EPI=0: fp32 out + bias (proj). EPI=1: bias + LN fused (q scaled by QSCALE),
//        write bf16 planes qp/kp/vp [M][12][64].
template<int EPI>
__global__ __launch_bounds__(256, 2) void gemm_f16(
    const _Float16* __restrict__ A,
    const _Float16* __restrict__ W,
    const float* __restrict__ bias,
    float* __restrict__ Out,
    short* __restrict__ qp, short* __restrict__ kp, short* __restrict__ vp,
    const float* __restrict__ qg, const float* __restrict__ qb,
    const float* __restrict__ kg, const float* __restrict__ kb,
    int nx)
{
    __shared__ _Float16 As[2][128 * 64];   // [buf][row][64k], 8-elem slot swizzle
    __shared__ _Float16 Bs[2][128 * 64];
    const int tid = threadIdx.x;
    const int lane = tid & 63;
    const int w = tid >> 6;
    const int wr = w >> 1, wc = w & 1;
    const int l15 = lane & 15, l4 = lane >> 4;
    const int lr = lane >> 3;
    const int lslot = lane & 7;

    // T1: bijective XCD chunking (gridDim.x % 8 == 0). Each XCD owns contiguous
    // A-bands; serpentine bx for W reuse across adjacent bands.
    {
    }
    const int chunk = gridDim.x >> 3;
    const int wg = (blockIdx.x & 7) * chunk + (blockIdx.x >> 3);
    const int by = wg / nx;
    int bx = wg % nx;
    if (by & 1) bx = nx - 1 - bx;
    const int m0 = by * 128;
    const int n0 = bx * 128;

    auto stage = [&](int kt, int buf) {
        const int k0 = kt * 64;
#pragma unroll
        for (int j = 0; j < 8; ++j) {
            int i = w * 8 + j;
            int isA = (i < 16);
            int ib = isA ? i : i - 16;
            int row = ib * 8 + lr;
            int gslot = lslot ^ (row & 7);
            const _Float16* src = (isA ? A + (size_t)(m0 + row) * 768
                                       : W + (size_t)(n0 + row) * 768) + k0 + gslot * 8;
            _Float16* dst = (isA ? &As[buf][0] : &Bs[buf][0]) + ib * 512;
            gld16(src, dst);
        }
    };

    f32x4 acc[4][4];
#pragma unroll
    for (int mi = 0; mi < 4; ++mi)
#pragma unroll
        for (int ni = 0; ni < 4; ++ni) { acc[mi][ni][0]=0.f; acc[mi][ni][1]=0.f; acc[mi][ni][2]=0.f; acc[mi][ni][3]=0.f; }

    stage(0, 0);
    __syncthreads();

    for (int kt = 0; kt < 12; ++kt) {
        const int cur = kt & 1;
        if (kt < 11) stage(kt + 1, cur ^ 1);   // prefetch; drained by end-of-iter barrier
#pragma unroll
        for (int ks = 0; ks < 2; ++ks) {
            f16x8 af[4], bfr[4];
#pragma unroll
            for (int mi = 0; mi < 4; ++mi) {
                int row = wr * 64 + mi * 16 + l15;
                int slot = (ks * 4 + l4) ^ (row & 7);
                af[mi] = ldf16(&As[cur][row * 64 + slot * 8]);
            }
#pragma unroll
            for (int ni = 0; ni < 4; ++ni) {
                int row = wc * 64 + ni * 16 + l15;
                int slot = (ks * 4 + l4) ^ (row & 7);
                bfr[ni] = ldf16(&Bs[cur][row * 64 + slot * 8]);
            }
#pragma unroll
            for (int mi = 0; mi < 4; ++mi)
#pragma unroll
                for (int ni = 0; ni < 4; ++ni)
                    acc[mi][ni] = MFMAH(af[mi], bfr[ni], acc[mi][ni]);
        }
        __syncthreads();
    }

    if (EPI == 0) {
#pragma unroll
        for (int mi = 0; mi < 4; ++mi)
#pragma unroll
            for (int r = 0; r < 4; ++r) {
                int row = m0 + wr * 64 + mi * 16 + l4 * 4 + r;
#pragma unroll
                for (int ni = 0; ni < 4; ++ni) {
                    int col = n0 + wc * 64 + ni * 16 + l15;
                    Out[(size_t)row * Cc + col] = acc[mi][ni][r] + bias[col];
                }
            }
    } else {
        const int ncol0 = n0 + wc * 64;
        const int type = ncol0 / Cc;           // 0=q 1=k 2=v
        const int h = (ncol0 % Cc) >> 6;
        const float* gptr = (type == 0) ? qg : kg;
        const float* bptr = (type == 0) ? qb : kb;
        float biasv[4], gv[4], bv[4];
#pragma unroll
        for (int ni = 0; ni < 4; ++ni) {
            int d = ni * 16 + l15;
            biasv[ni] = bias[ncol0 + d];
            if (type < 2) { gv[ni] = gptr[d]; bv[ni] = bptr[d]; }
        }
        short* plane = (type == 0) ? qp : (type == 1) ? kp : vp;
#pragma unroll
        for (int mi = 0; mi < 4; ++mi)
#pragma unroll
            for (int r = 0; r < 4; ++r) {
                float v[4];
#pragma unroll
                for (int ni = 0; ni < 4; ++ni) v[ni] = acc[mi][ni][r] + biasv[ni];
                int row = m0 + wr * 64 + mi * 16 + l4 * 4 + r;
                size_t base = ((size_t)row * Hh + h) * 64;
                if (type < 2) {
                    float s = v[0] + v[1] + v[2] + v[3];
#pragma unroll
                    for (int off = 1; off < 16; off <<= 1) s += __shfl_xor(s, off);
                    float mu = s * (1.0f / 64.0f);
                    float s2 = 0.f;
#pragma unroll
                    for (int ni = 0; ni < 4; ++ni) { float dv = v[ni] - mu; s2 += dv * dv; }
#pragma unroll
                    for (int off = 1; off < 16; off <<= 1) s2 += __shfl_xor(s2, off);
                    float inv = rsqrtf(s2 * (1.0f / 64.0f) + EPS);
#pragma unroll
                    for (int ni = 0; ni < 4; ++ni) {
                        float rr = (v[ni] - mu) * inv * gv[ni] + bv[ni];
                        if (type == 0) rr *= QSCALE;
                        plane[base + ni * 16 + l15] = f2b(rr);
                    }
                } else {
#pragma unroll
                    for (int ni = 0; ni < 4; ++ni)
                        plane[base + ni * 16 + l15] = f2b(v[ni]);
                }
            }
    }
}

// ---------------- Flash attention: 32x32 MFMA, swapped QK^T, in-register P ----------------
// 4 waves x 32 q-rows = 128 q/block. K/V 64-tiles double-buffered in 32KB LDS.
// S^T = mfma(K,Q) puts each q-row lane-local: softmax is per-lane scalar; P->A-frag
// via cvt_pk_bf16 + shfl_xor(32) (no LDS round trip).
__global__ __launch_bounds__(256, 4) void flash_attn_mfma(
    const short* __restrict__ qp, const short* __restrict__ kp, const short* __restrict__ vp,
    _Float16* __restrict__ att)
{
    __shared__ short kls[2][64 * 64];    // K tile [k][d], 16B-slot XOR swizzle
    __shared__ short vtl[2][64 * 64];    // V^T tile [d][k], same swizzle
    const int tid = threadIdx.x;
    const int lane = tid & 63;
    const int w = tid >> 6;              // 0..3
    const int l31 = lane & 31;
    const int hi = lane >> 5;            // 0/1
    const int lr = lane >> 3;            // 0..7
    const int lslot = lane & 7;
    // XCD-aware swizzle: 768 = 8 XCD * 96 (bijective)
    const int bid = (blockIdx.x & 7) * 96 + (blockIdx.x >> 3);
    const int qt = bid & 7;
    const int bh = bid >> 3;
    const int h = bh % Hh;
    const int b = bh / Hh;
    const int q0 = qt * 128;
    const size_t hbase = ((size_t)b * Nn * Hh + h) * 64;
    const int n0v = (tid & 31) * 2, d0v = (tid >> 5) * 8;

    // Q fragments (B-operand layout): qf[ds] = Q[q=l31][ds*16 + hi*8 .. +7]
    bf16x8 qf[4];
    {
        const short* qsrc = qp + hbase + (size_t)(q0 + w * 32 + l31) * 768 + hi * 8;
#pragma unroll
        for (int ds = 0; ds < 4; ++ds)
            qf[ds] = *(const bf16x8*)(qsrc + ds * 16);
    }

    // prologue: stage K0 + V0
#pragma unroll
    for (int i = 0; i < 2; ++i) {
        int rl = i * 32 + w * 8 + lr;
        gld16(kp + hbase + (size_t)rl * 768 + (lslot ^ lr) * 8,
              &kls[0][(i * 32 + w * 8) * 64]);
    }
    {
        const short* s0 = vp + hbase + (size_t)n0v * 768 + d0v;
        bf16x8 a0 = *(const bf16x8*)s0;
        bf16x8 a1 = *(const bf16x8*)(s0 + 768);
#pragma unroll
        for (int j = 0; j < 8; ++j) {
            int d = d0v + j;
            unsigned pk = (unsigned short)a0[j] | ((unsigned)(unsigned short)a1[j] << 16);
            *(unsigned*)&vtl[0][d * 64 + (((n0v >> 3) ^ (d & 7)) << 3) + (n0v & 7)] = pk;
        }
    }
    __syncthreads();

    f32x16 o0, o1;
#pragma unroll
    for (int i = 0; i < 16; ++i) { o0[i] = 0.f; o1[i] = 0.f; }
    float lrun = 0.f;
    unsigned afu[4][4];

    for (int kt = 0; kt < 16; ++kt) {
        const int cur = kt & 1, nxt = cur ^ 1;
        // T14: issue next K (gld) + load next V to regs now; commit V after PV
        bf16x8 va0, va1;
        if (kt < 15) {
#pragma unroll
            for (int i = 0; i < 2; ++i) {
                int rl = i * 32 + w * 8 + lr;
                gld16(kp + hbase + (size_t)((kt + 1) * 64 + rl) * 768 + (lslot ^ lr) * 8,
                      &kls[nxt][(i * 32 + w * 8) * 64]);
            }
            const short* s0 = vp + hbase + (size_t)((kt + 1) * 64 + n0v) * 768 + d0v;
            va0 = *(const bf16x8*)s0;
            va1 = *(const bf16x8*)(s0 + 768);
        }
        // S^T = mfma(K, Q): lane holds P[k-set][q=l31]; per 32-k tile 16 values
#pragma unroll
        for (int t2 = 0; t2 < 2; ++t2) {
            f32x16 st;
#pragma unroll
            for (int i = 0; i < 16; ++i) st[i] = 0.f;
            const int row = t2 * 32 + l31;
            const int rsw = row & 7;
#pragma unroll
            for (int ds = 0; ds < 4; ++ds) {
                bf16x8 kf = *(const bf16x8*)&kls[cur][row * 64 + (((ds * 2 + hi) ^ rsw) << 3)];
                st = MFMA32(kf, qf[ds], st);
            }
            // exp2 in place + per-lane partial row sum (q = l31 fixed per lane)
#pragma unroll
            for (int i = 0; i < 16; ++i) { st[i] = exp2f(st[i]); lrun += st[i]; }
            // pack pairs (adjacent k) then exchange halves: build PV A-frags in regs
            unsigned pk[8], sx[8];
#pragma unroll
            for (int i = 0; i < 8; ++i) pk[i] = cvtpk(st[2 * i], st[2 * i + 1]);
#pragma unroll
            for (int i = 0; i < 8; ++i) sx[i] = (unsigned)__shfl_xor((int)pk[i], 32);
            afu[t2 * 2 + 0][0] = hi ? sx[2] : pk[0];
            afu[t2 * 2 + 0][1] = hi ? sx[3] : pk[1];
            afu[t2 * 2 + 0][2] = hi ? pk[2] : sx[0];
            afu[t2 * 2 + 0][3] = hi ? pk[3] : sx[1];
            afu[t2 * 2 + 1][0] = hi ? sx[6] : pk[4];
            afu[t2 * 2 + 1][1] = hi ? sx[7] : pk[5];
            afu[t2 * 2 + 1][2] = hi ? pk[6] : sx[4];
            afu[t2 * 2 + 1][3] = hi ? pk[7] : sx[5];
        }
        // O += P V  (two independent d-tiles)
        __builtin_amdgcn_s_setprio(1);
#pragma unroll
        for (int c = 0; c < 4; ++c) {
            union { bf16x8 v; unsigned u[4]; } a;
            a.u[0] = afu[c][0]; a.u[1] = afu[c][1]; a.u[2] = afu[c][2]; a.u[3] = afu[c][3];
            const int r0 = l31, r1 = 32 + l31;
            const int sw = l31 & 7;
            bf16x8 vf0 = *(const bf16x8*)&vtl[cur][r0 * 64 + (((c * 2 + hi) ^ sw) << 3)];
            bf16x8 vf1 = *(const bf16x8*)&vtl[cur][r1 * 64 + (((c * 2 + hi) ^ sw) << 3)];
            o0 = MFMA32(a.v, vf0, o0);
            o1 = MFMA32(a.v, vf1, o1);
        }
        __builtin_amdgcn_s_setprio(0);
        // commit prefetched V to the other buffer
        if (kt < 15) {
#pragma unroll
            for (int j = 0; j < 8; ++j) {
                int d = d0v + j;
                unsigned pk = (unsigned short)va0[j] | ((unsigned)(unsigned short)va1[j] << 16);
                *(unsigned*)&vtl[nxt][d * 64 + (((n0v >> 3) ^ (d & 7)) << 3) + (n0v & 7)] = pk;
            }
        }
        __syncthreads();
    }

    // epilogue: complete row sums across halves, divide, store fp16
    lrun += __shfl_xor(lrun, 32);
    float linv = 1.0f / lrun;            // inv for q = l31
#pragma unroll
    for (int r = 0; r < 16; ++r) {
        int qr = (r & 3) + 8 * (r >> 2) + 4 * hi;
        float invr = __shfl(linv, qr);
        int row = q0 + w * 32 + qr;
        _Float16* dst = att + (size_t)(b * Nn + row) * Cc + h * 64 + l31;
        dst[0]  = (_Float16)(o0[r] * invr);
        dst[32] = (_Float16)(o1[r] * invr);
    }
}

extern "C" void kernel_launch(void* const* d_in, const int* in_sizes, int n_in,
                              void* d_out, int out_size, void* d_ws, size_t ws_size,
                              hipStream_t stream)
{
    const float* x      = (const float*)d_in[0];
    const float* qkv_w  = (const float*)d_in[1];
    const float* qkv_b  = (const float*)d_in[2];
    const float* qn_g   = (const float*)d_in[3];
    const float* qn_b   = (const float*)d_in[4];
    const float* kn_g   = (const float*)d_in[5];
    const float* kn_b   = (const float*)d_in[6];
    const float* proj_w = (const float*)d_in[7];
    const float* proj_b = (const float*)d_in[8];
    float* out = (float*)d_out;

    char* ws = (char*)d_ws;
    short*    qp  = (short*)(ws);                          // [8192][12][64] bf16
    short*    kp  = (short*)(ws + 12582912);
    short*    vp  = (short*)(ws + 25165824);
    _Float16* att = (_Float16*)(ws + 37748736);            // [8192][768] fp16
    _Float16* xh  = (_Float16*)(ws + 50331648);            // [8192][768] fp16
    _Float16* wqh = (_Float16*)(ws + 62914560);            // [2304][768] fp16
    _Float16* wph = (_Float16*)(ws + 66453504);            // [768][768] fp16

    // 0) fused fp32 -> fp16 conversions
    {
        const int n3 = BN * Cc / 8 + C3 * Cc / 8 + Cc * Cc / 8;
        cvt_all<<<(n3 + 255) / 256, 256, 0, stream>>>(x, qkv_w, proj_w, xh, wqh, wph);
    }
    // 1) QKV GEMM + bias + fused LN (q scaled by 0.125*log2e) -> bf16 q/k/v planes
    gemm_f16<1><<<(BN / 128) * (C3 / 128), 256, 0, stream>>>(
        xh, wqh, qkv_b, nullptr, qp, kp, vp, qn_g, qn_b, kn_g, kn_b, C3 / 128);
    // 2) flash attention -> fp16 att
    flash_attn_mfma<<<Bz * Hh * 8, 256, 0, stream>>>(qp, kp, vp, att);
    // 3) output projection + bias -> fp32 out
    gemm_f16<0><<<(BN / 128) * (Cc / 128), 256, 0, stream>>>(
        att, wph, proj_b, out, nullptr, nullptr, nullptr, nullptr, nullptr, nullptr, nullptr, Cc / 128);
}